// Round 1
// baseline (830.059 us; speedup 1.0000x reference)
//
#include <hip/hip_runtime.h>
#include <stdint.h>

#define NN 50000
#define NE 800000
#define DIM 256

// ---------------- degree histogram ----------------
__global__ void deg_kernel(const int* __restrict__ src, const int* __restrict__ dst,
                           int* __restrict__ out_cnt, int* __restrict__ in_cnt) {
  int e = blockIdx.x * blockDim.x + threadIdx.x;
  if (e < NE) {
    atomicAdd(&out_cnt[src[e]], 1);
    atomicAdd(&in_cnt[dst[e]], 1);
  }
}

// ---------------- norms ----------------
__global__ void norm_kernel(const int* __restrict__ out_cnt, const int* __restrict__ in_cnt,
                            float* __restrict__ norm_s, float* __restrict__ norm_d) {
  int i = blockIdx.x * blockDim.x + threadIdx.x;
  if (i < NN) {
    norm_s[i] = rsqrtf(fmaxf((float)out_cnt[i], 1.0f));
    norm_d[i] = rsqrtf(fmaxf((float)in_cnt[i], 1.0f));
  }
}

// ---------------- exclusive scan (single block, 1024 thr, 4 elem/thr) ----------------
__global__ __launch_bounds__(1024) void scan_kernel(const int* __restrict__ in_cnt,
                                                    int* __restrict__ row_ptr,
                                                    int* __restrict__ cursor) {
  __shared__ int wsum[16];
  int tid = threadIdx.x;
  int lane = tid & 63, wave = tid >> 6;
  int carry = 0;
  for (int base = 0; base < NN; base += 4096) {
    int i0 = base + tid * 4;
    int v[4];
#pragma unroll
    for (int j = 0; j < 4; ++j) {
      int i = i0 + j;
      v[j] = (i < NN) ? in_cnt[i] : 0;
    }
    int tsum = v[0] + v[1] + v[2] + v[3];
    // wave-inclusive scan of tsum
    int incl = tsum;
#pragma unroll
    for (int off = 1; off < 64; off <<= 1) {
      int t = __shfl_up(incl, off, 64);
      if (lane >= off) incl += t;
    }
    if (lane == 63) wsum[wave] = incl;
    __syncthreads();
    int waveoff = 0;
    for (int w = 0; w < wave; ++w) waveoff += wsum[w];
    int chunk_total = 0;
    for (int w = 0; w < 16; ++w) chunk_total += wsum[w];
    int run = carry + waveoff + (incl - tsum);
#pragma unroll
    for (int j = 0; j < 4; ++j) {
      int i = i0 + j;
      if (i < NN) { row_ptr[i] = run; cursor[i] = run; }
      run += v[j];
    }
    carry += chunk_total;
    __syncthreads();
  }
  if (tid == 0) row_ptr[NN] = carry;  // == NE
}

// ---------------- CSR fill ----------------
__global__ void fill_kernel(const int* __restrict__ src, const int* __restrict__ dst,
                            int* __restrict__ cursor, int* __restrict__ colx) {
  int e = blockIdx.x * blockDim.x + threadIdx.x;
  if (e < NE) {
    int p = atomicAdd(&cursor[dst[e]], 1);
    colx[p] = src[e];
  }
}

// ---------------- gather-aggregate: agg[n] = norm_d[n] * sum_{e->n} norm_s[c]*X[c] ----------------
__global__ __launch_bounds__(256) void agg_kernel(const float* __restrict__ X,
                                                  float* __restrict__ agg,
                                                  const int* __restrict__ row_ptr,
                                                  const int* __restrict__ colx,
                                                  const float* __restrict__ norm_s,
                                                  const float* __restrict__ norm_d) {
  int wave = threadIdx.x >> 6;
  int lane = threadIdx.x & 63;
  int node = blockIdx.x * 4 + wave;
  if (node >= NN) return;
  int beg = row_ptr[node];
  int end = row_ptr[node + 1];
  float ax = 0.f, ay = 0.f, az = 0.f, aw = 0.f;
  for (int i = beg; i < end; ++i) {
    int c = colx[i];
    float s = norm_s[c];
    const float4 x = *(const float4*)(X + (size_t)c * DIM + lane * 4);
    ax += x.x * s; ay += x.y * s; az += x.z * s; aw += x.w * s;
  }
  float nd = norm_d[node];
  float4 o; o.x = ax * nd; o.y = ay * nd; o.z = az * nd; o.w = aw * nd;
  *(float4*)(agg + (size_t)node * DIM + lane * 4) = o;
}

// ---------------- GEMM + bias + PReLU + column-sum pooling ----------------
// C[row] = prelu(A[row] @ W + b); hg[n] += sum_rows C[row][n]
// block: 256 thr = 4 waves; block computes 64 rows x 256 cols.
// wave w -> rows r0=w*16..+16, lane -> cols n0=lane*4..+4
__global__ __launch_bounds__(256) void gemm_kernel(const float* __restrict__ A,
                                                   const float* __restrict__ W,
                                                   const float* __restrict__ bias,
                                                   const float* __restrict__ prelu_a_ptr,
                                                   float* __restrict__ C,
                                                   float* __restrict__ hg) {
  __shared__ float As[64 * DIM];  // 64 KB
  int tid = threadIdx.x;
  int row0 = blockIdx.x * 64;
  // stage A tile
  for (int idx = tid; idx < 64 * 64; idx += 256) {
    int r = idx >> 6;
    int cc = idx & 63;
    int row = row0 + r;
    float4 v;
    if (row < NN) v = *(const float4*)(A + (size_t)row * DIM + cc * 4);
    else { v.x = v.y = v.z = v.w = 0.f; }
    *(float4*)(&As[r * DIM + cc * 4]) = v;
  }
  __syncthreads();

  int wave = tid >> 6, lane = tid & 63;
  int r0 = wave * 16;
  int n0 = lane * 4;
  const float* Ap = &As[r0 * DIM];

  float acc[16][4];
#pragma unroll
  for (int r = 0; r < 16; ++r) { acc[r][0] = 0.f; acc[r][1] = 0.f; acc[r][2] = 0.f; acc[r][3] = 0.f; }

  for (int k = 0; k < DIM; k += 4) {
    const float4 w0 = *(const float4*)(W + (size_t)(k + 0) * DIM + n0);
    const float4 w1 = *(const float4*)(W + (size_t)(k + 1) * DIM + n0);
    const float4 w2 = *(const float4*)(W + (size_t)(k + 2) * DIM + n0);
    const float4 w3 = *(const float4*)(W + (size_t)(k + 3) * DIM + n0);
#pragma unroll
    for (int r = 0; r < 16; ++r) {
      const float4 a4 = *(const float4*)(&Ap[r * DIM + k]);
      acc[r][0] += a4.x * w0.x + a4.y * w1.x + a4.z * w2.x + a4.w * w3.x;
      acc[r][1] += a4.x * w0.y + a4.y * w1.y + a4.z * w2.y + a4.w * w3.y;
      acc[r][2] += a4.x * w0.z + a4.y * w1.z + a4.z * w2.z + a4.w * w3.z;
      acc[r][3] += a4.x * w0.w + a4.y * w1.w + a4.z * w2.w + a4.w * w3.w;
    }
  }

  float pa = *prelu_a_ptr;
  const float4 b4 = *(const float4*)(bias + n0);
  float cs0 = 0.f, cs1 = 0.f, cs2 = 0.f, cs3 = 0.f;
#pragma unroll
  for (int r = 0; r < 16; ++r) {
    int row = row0 + r0 + r;
    if (row < NN) {
      float x0 = acc[r][0] + b4.x; x0 = (x0 >= 0.f) ? x0 : pa * x0;
      float x1 = acc[r][1] + b4.y; x1 = (x1 >= 0.f) ? x1 : pa * x1;
      float x2 = acc[r][2] + b4.z; x2 = (x2 >= 0.f) ? x2 : pa * x2;
      float x3 = acc[r][3] + b4.w; x3 = (x3 >= 0.f) ? x3 : pa * x3;
      float4 o; o.x = x0; o.y = x1; o.z = x2; o.w = x3;
      *(float4*)(C + (size_t)row * DIM + n0) = o;
      cs0 += x0; cs1 += x1; cs2 += x2; cs3 += x3;
    }
  }
  // block-level column-sum reduction (reuse As)
  __syncthreads();
  float4* red = (float4*)As;  // [4][64]
  float4 t; t.x = cs0; t.y = cs1; t.z = cs2; t.w = cs3;
  red[wave * 64 + lane] = t;
  __syncthreads();
  if (wave == 0) {
    float4 a0 = red[lane];
    float4 a1 = red[64 + lane];
    float4 a2 = red[128 + lane];
    float4 a3 = red[192 + lane];
    float s0 = a0.x + a1.x + a2.x + a3.x;
    float s1 = a0.y + a1.y + a2.y + a3.y;
    float s2 = a0.z + a1.z + a2.z + a3.z;
    float s3 = a0.w + a1.w + a2.w + a3.w;
    atomicAdd(&hg[n0 + 0], s0);
    atomicAdd(&hg[n0 + 1], s1);
    atomicAdd(&hg[n0 + 2], s2);
    atomicAdd(&hg[n0 + 3], s3);
  }
}

extern "C" void kernel_launch(void* const* d_in, const int* in_sizes, int n_in,
                              void* d_out, int out_size, void* d_ws, size_t ws_size,
                              hipStream_t stream) {
  const float* feat = (const float*)d_in[0];
  const int* src    = (const int*)d_in[1];
  const int* dst    = (const int*)d_in[2];
  const float* W0   = (const float*)d_in[3];
  const float* b0   = (const float*)d_in[4];
  const float* W1   = (const float*)d_in[5];
  const float* b1   = (const float*)d_in[6];
  const float* pa   = (const float*)d_in[7];

  float* out_h = (float*)d_out;                      // [NN, DIM]
  float* hg    = out_h + (size_t)NN * DIM;           // [512]

  // workspace layout
  char* w = (char*)d_ws;
  int* out_cnt  = (int*)w;        w += (size_t)NN * 4;
  int* in_cnt   = (int*)w;        w += (size_t)NN * 4;
  float* norm_s = (float*)w;      w += (size_t)NN * 4;
  float* norm_d = (float*)w;      w += (size_t)NN * 4;
  int* row_ptr  = (int*)w;        w += (size_t)(NN + 1) * 4;
  int* cursor   = (int*)w;        w += (size_t)NN * 4;
  int* colx     = (int*)w;        w += (size_t)NE * 4;
  uintptr_t ap = ((uintptr_t)w + 255) & ~(uintptr_t)255;
  float* aggbuf = (float*)ap;     // [NN, DIM] f32 = 51.2 MB

  float* h1 = out_h;  // layer-1 activations live in the output h region (overwritten later)

  // zero counters (contiguous) and pooled output
  hipMemsetAsync(out_cnt, 0, (size_t)NN * 2 * sizeof(int), stream);
  hipMemsetAsync(hg, 0, 512 * sizeof(float), stream);

  deg_kernel<<<(NE + 255) / 256, 256, 0, stream>>>(src, dst, out_cnt, in_cnt);
  norm_kernel<<<(NN + 255) / 256, 256, 0, stream>>>(out_cnt, in_cnt, norm_s, norm_d);
  scan_kernel<<<1, 1024, 0, stream>>>(in_cnt, row_ptr, cursor);
  fill_kernel<<<(NE + 255) / 256, 256, 0, stream>>>(src, dst, cursor, colx);

  // layer 1
  agg_kernel<<<(NN + 3) / 4, 256, 0, stream>>>(feat, aggbuf, row_ptr, colx, norm_s, norm_d);
  gemm_kernel<<<(NN + 63) / 64, 256, 0, stream>>>(aggbuf, W0, b0, pa, h1, hg);

  // layer 2
  agg_kernel<<<(NN + 3) / 4, 256, 0, stream>>>(h1, aggbuf, row_ptr, colx, norm_s, norm_d);
  gemm_kernel<<<(NN + 63) / 64, 256, 0, stream>>>(aggbuf, W1, b1, pa, out_h, hg + 256);
}

// Round 2
// 555.356 us; speedup vs baseline: 1.4946x; 1.4946x over previous
//
#include <hip/hip_runtime.h>
#include <stdint.h>

#define NN 50000
#define NE 800000
#define DIM 256

typedef __bf16 bf16x8 __attribute__((ext_vector_type(8)));
typedef float f32x4 __attribute__((ext_vector_type(4)));

__device__ __forceinline__ unsigned short f2bf(float f) {
  union { float f; unsigned u; } v; v.f = f;
  unsigned r = v.u + 0x7fffu + ((v.u >> 16) & 1u);
  return (unsigned short)(r >> 16);
}
__device__ __forceinline__ float bf2f(unsigned short h) {
  union { unsigned u; float f; } v; v.u = ((unsigned)h) << 16;
  return v.f;
}

// ---------------- degree histogram ----------------
__global__ void deg_kernel(const int* __restrict__ src, const int* __restrict__ dst,
                           int* __restrict__ out_cnt, int* __restrict__ in_cnt) {
  int e = blockIdx.x * blockDim.x + threadIdx.x;
  if (e < NE) {
    atomicAdd(&out_cnt[src[e]], 1);
    atomicAdd(&in_cnt[dst[e]], 1);
  }
}

// ---------------- norms ----------------
__global__ void norm_kernel(const int* __restrict__ out_cnt, const int* __restrict__ in_cnt,
                            float* __restrict__ norm_s, float* __restrict__ norm_d) {
  int i = blockIdx.x * blockDim.x + threadIdx.x;
  if (i < NN) {
    norm_s[i] = rsqrtf(fmaxf((float)out_cnt[i], 1.0f));
    norm_d[i] = rsqrtf(fmaxf((float)in_cnt[i], 1.0f));
  }
}

// ---------------- exclusive scan (single block) ----------------
__global__ __launch_bounds__(1024) void scan_kernel(const int* __restrict__ in_cnt,
                                                    int* __restrict__ row_ptr,
                                                    int* __restrict__ cursor) {
  __shared__ int wsum[16];
  int tid = threadIdx.x;
  int lane = tid & 63, wave = tid >> 6;
  int carry = 0;
  for (int base = 0; base < NN; base += 4096) {
    int i0 = base + tid * 4;
    int v[4];
#pragma unroll
    for (int j = 0; j < 4; ++j) {
      int i = i0 + j;
      v[j] = (i < NN) ? in_cnt[i] : 0;
    }
    int tsum = v[0] + v[1] + v[2] + v[3];
    int incl = tsum;
#pragma unroll
    for (int off = 1; off < 64; off <<= 1) {
      int t = __shfl_up(incl, off, 64);
      if (lane >= off) incl += t;
    }
    if (lane == 63) wsum[wave] = incl;
    __syncthreads();
    int waveoff = 0;
    for (int w = 0; w < wave; ++w) waveoff += wsum[w];
    int chunk_total = 0;
    for (int w = 0; w < 16; ++w) chunk_total += wsum[w];
    int run = carry + waveoff + (incl - tsum);
#pragma unroll
    for (int j = 0; j < 4; ++j) {
      int i = i0 + j;
      if (i < NN) { row_ptr[i] = run; cursor[i] = run; }
      run += v[j];
    }
    carry += chunk_total;
    __syncthreads();
  }
  if (tid == 0) row_ptr[NN] = carry;
}

// ---------------- CSR fill ----------------
__global__ void fill_kernel(const int* __restrict__ src, const int* __restrict__ dst,
                            int* __restrict__ cursor, int* __restrict__ colx) {
  int e = blockIdx.x * blockDim.x + threadIdx.x;
  if (e < NE) {
    int p = atomicAdd(&cursor[dst[e]], 1);
    colx[p] = src[e];
  }
}

// ---------------- f32 -> bf16 cast (4 elems/thread) ----------------
__global__ void cast_kernel(const float* __restrict__ in, unsigned short* __restrict__ out, int n4) {
  int i = blockIdx.x * blockDim.x + threadIdx.x;
  if (i < n4) {
    float4 v = ((const float4*)in)[i];
    ushort4 o;
    o.x = f2bf(v.x); o.y = f2bf(v.y); o.z = f2bf(v.z); o.w = f2bf(v.w);
    ((ushort4*)out)[i] = o;
  }
}

// ---------------- W (256x256 f32 row-major, K x N) -> MFMA B-frag swizzled bf16 ----------------
// Wb[(((nt*8 + kc)*64 + lane)*8 + j] = bf16( W[(kc*32 + (lane>>4)*8 + j)*256 + nt*16 + (lane&15)] )
__global__ void swizzleW_kernel(const float* __restrict__ W, unsigned short* __restrict__ Wb) {
  int idx = blockIdx.x * blockDim.x + threadIdx.x;  // 0 .. 8191
  if (idx >= 16 * 8 * 64) return;
  int lane = idx & 63;
  int blk = idx >> 6;
  int kc = blk & 7, nt = blk >> 3;
  int kbase = kc * 32 + (lane >> 4) * 8;
  int col = nt * 16 + (lane & 15);
  ushort4 o0, o1;
  o0.x = f2bf(W[(size_t)(kbase + 0) * DIM + col]);
  o0.y = f2bf(W[(size_t)(kbase + 1) * DIM + col]);
  o0.z = f2bf(W[(size_t)(kbase + 2) * DIM + col]);
  o0.w = f2bf(W[(size_t)(kbase + 3) * DIM + col]);
  o1.x = f2bf(W[(size_t)(kbase + 4) * DIM + col]);
  o1.y = f2bf(W[(size_t)(kbase + 5) * DIM + col]);
  o1.z = f2bf(W[(size_t)(kbase + 6) * DIM + col]);
  o1.w = f2bf(W[(size_t)(kbase + 7) * DIM + col]);
  ((ushort4*)Wb)[idx * 2 + 0] = o0;
  ((ushort4*)Wb)[idx * 2 + 1] = o1;
}

// ---------------- gather-aggregate (bf16 in, bf16 out): agg[n] = nd[n]*sum norm_s[c]*X[c] ----------------
__global__ __launch_bounds__(256) void agg_kernel(const unsigned short* __restrict__ X,
                                                  unsigned short* __restrict__ agg,
                                                  const int* __restrict__ row_ptr,
                                                  const int* __restrict__ colx,
                                                  const float* __restrict__ norm_s,
                                                  const float* __restrict__ norm_d) {
  int wave = threadIdx.x >> 6;
  int lane = threadIdx.x & 63;
  int node = blockIdx.x * 4 + wave;
  if (node >= NN) return;
  int beg = row_ptr[node];
  int end = row_ptr[node + 1];
  float a0 = 0.f, a1 = 0.f, a2 = 0.f, a3 = 0.f;
  for (int i = beg; i < end; ++i) {
    int c = colx[i];
    float s = norm_s[c];
    ushort4 x = *(const ushort4*)(X + (size_t)c * DIM + lane * 4);
    a0 += bf2f(x.x) * s;
    a1 += bf2f(x.y) * s;
    a2 += bf2f(x.z) * s;
    a3 += bf2f(x.w) * s;
  }
  float nd = norm_d[node];
  ushort4 o;
  o.x = f2bf(a0 * nd); o.y = f2bf(a1 * nd); o.z = f2bf(a2 * nd); o.w = f2bf(a3 * nd);
  *(ushort4*)(agg + (size_t)node * DIM + lane * 4) = o;
}

// ---------------- MFMA GEMM + bias + PReLU + (bf16 copy) + column-sum pooling ----------------
// block = 256 thr (4 waves); tile 64 rows x 256 cols; wave w -> cols [w*64, w*64+64)
#define LDSROW 264  // 256 + 8 bf16 pad (keeps 16B align, spreads banks)
__global__ __launch_bounds__(256) void gemm_mfma_kernel(const unsigned short* __restrict__ A,
                                                        const unsigned short* __restrict__ Wb,
                                                        const float* __restrict__ bias,
                                                        const float* __restrict__ prelu_a_ptr,
                                                        float* __restrict__ C,
                                                        unsigned short* __restrict__ Cb,
                                                        float* __restrict__ hg) {
  __shared__ unsigned short As[64 * LDSROW];
  int tid = threadIdx.x;
  int r0 = blockIdx.x * 64;
  // stage A tile: 64 rows x 256 bf16 (512 B/row), 16 B per thread per pass, 8 passes
#pragma unroll
  for (int p = 0; p < 8; ++p) {
    int idx = p * 256 + tid;
    int row = idx >> 5;   // 0..63
    int seg = idx & 31;   // 16B segment within row
    int grow = r0 + row;
    ushort4 v0 = {0, 0, 0, 0}, v1 = {0, 0, 0, 0};
    if (grow < NN) {
      const ushort4* g = (const ushort4*)(A + (size_t)grow * DIM + seg * 8);
      v0 = g[0]; v1 = g[1];
    }
    *(ushort4*)(&As[row * LDSROW + seg * 8 + 0]) = v0;
    *(ushort4*)(&As[row * LDSROW + seg * 8 + 4]) = v1;
  }
  __syncthreads();

  int wave = tid >> 6, lane = tid & 63;
  int quad = lane >> 4, l16 = lane & 15;

  f32x4 acc[4][4];
#pragma unroll
  for (int mt = 0; mt < 4; ++mt)
#pragma unroll
    for (int nti = 0; nti < 4; ++nti)
      acc[mt][nti] = (f32x4){0.f, 0.f, 0.f, 0.f};

#pragma unroll
  for (int kc = 0; kc < 8; ++kc) {
    bf16x8 a[4], b[4];
#pragma unroll
    for (int mt = 0; mt < 4; ++mt)
      a[mt] = *(const bf16x8*)(&As[(mt * 16 + l16) * LDSROW + kc * 32 + quad * 8]);
#pragma unroll
    for (int nti = 0; nti < 4; ++nti) {
      int nt = wave * 4 + nti;
      b[nti] = *(const bf16x8*)(Wb + ((size_t)(nt * 8 + kc) * 64 + lane) * 8);
    }
#pragma unroll
    for (int mt = 0; mt < 4; ++mt)
#pragma unroll
      for (int nti = 0; nti < 4; ++nti)
        acc[mt][nti] = __builtin_amdgcn_mfma_f32_16x16x32_bf16(a[mt], b[nti], acc[mt][nti], 0, 0, 0);
  }

  float pa = *prelu_a_ptr;
  float bv[4], cs[4];
#pragma unroll
  for (int nti = 0; nti < 4; ++nti) {
    bv[nti] = bias[wave * 64 + nti * 16 + l16];
    cs[nti] = 0.f;
  }

#pragma unroll
  for (int mt = 0; mt < 4; ++mt) {
#pragma unroll
    for (int nti = 0; nti < 4; ++nti) {
      int colg = wave * 64 + nti * 16 + l16;
#pragma unroll
      for (int r = 0; r < 4; ++r) {
        int rowg = r0 + mt * 16 + quad * 4 + r;
        if (rowg < NN) {
          float x = acc[mt][nti][r] + bv[nti];
          x = (x >= 0.f) ? x : pa * x;
          C[(size_t)rowg * DIM + colg] = x;
          if (Cb) Cb[(size_t)rowg * DIM + colg] = f2bf(x);
          cs[nti] += x;
        }
      }
    }
  }
  // reduce column sums across the 4 quads (lanes l16, l16+16, l16+32, l16+48 share a column)
#pragma unroll
  for (int nti = 0; nti < 4; ++nti) {
    cs[nti] += __shfl_xor(cs[nti], 16, 64);
    cs[nti] += __shfl_xor(cs[nti], 32, 64);
  }
  if (quad == 0) {
#pragma unroll
    for (int nti = 0; nti < 4; ++nti)
      atomicAdd(&hg[wave * 64 + nti * 16 + l16], cs[nti]);
  }
}

extern "C" void kernel_launch(void* const* d_in, const int* in_sizes, int n_in,
                              void* d_out, int out_size, void* d_ws, size_t ws_size,
                              hipStream_t stream) {
  const float* feat = (const float*)d_in[0];
  const int* src    = (const int*)d_in[1];
  const int* dst    = (const int*)d_in[2];
  const float* W0   = (const float*)d_in[3];
  const float* b0   = (const float*)d_in[4];
  const float* W1   = (const float*)d_in[5];
  const float* b1   = (const float*)d_in[6];
  const float* pa   = (const float*)d_in[7];

  float* out_h = (float*)d_out;                      // [NN, DIM] f32
  float* hg    = out_h + (size_t)NN * DIM;           // [512] f32

  // workspace layout
  char* w = (char*)d_ws;
  int* out_cnt  = (int*)w;        w += (size_t)NN * 4;
  int* in_cnt   = (int*)w;        w += (size_t)NN * 4;
  float* norm_s = (float*)w;      w += (size_t)NN * 4;
  float* norm_d = (float*)w;      w += (size_t)NN * 4;
  int* row_ptr  = (int*)w;        w += (size_t)(NN + 1) * 4;
  int* cursor   = (int*)w;        w += (size_t)NN * 4;
  int* colx     = (int*)w;        w += (size_t)NE * 4;
  unsigned short* Wb0 = (unsigned short*)w;  w += (size_t)DIM * DIM * 2;
  unsigned short* Wb1 = (unsigned short*)w;  w += (size_t)DIM * DIM * 2;
  uintptr_t ap = ((uintptr_t)w + 255) & ~(uintptr_t)255;
  unsigned short* featb = (unsigned short*)ap;                 // [NN,DIM] bf16 (reused as h1b)
  unsigned short* aggb  = featb + (size_t)NN * DIM;            // [NN,DIM] bf16

  hipMemsetAsync(out_cnt, 0, (size_t)NN * 2 * sizeof(int), stream);
  hipMemsetAsync(hg, 0, 512 * sizeof(float), stream);

  deg_kernel<<<(NE + 255) / 256, 256, 0, stream>>>(src, dst, out_cnt, in_cnt);
  norm_kernel<<<(NN + 255) / 256, 256, 0, stream>>>(out_cnt, in_cnt, norm_s, norm_d);
  scan_kernel<<<1, 1024, 0, stream>>>(in_cnt, row_ptr, cursor);
  fill_kernel<<<(NE + 255) / 256, 256, 0, stream>>>(src, dst, cursor, colx);

  cast_kernel<<<(NN * DIM / 4 + 255) / 256, 256, 0, stream>>>(feat, featb, NN * DIM / 4);
  swizzleW_kernel<<<32, 256, 0, stream>>>(W0, Wb0);
  swizzleW_kernel<<<32, 256, 0, stream>>>(W1, Wb1);

  // layer 1
  agg_kernel<<<(NN + 3) / 4, 256, 0, stream>>>(featb, aggb, row_ptr, colx, norm_s, norm_d);
  // h1 f32 -> out_h (overwritten by layer 2), h1 bf16 -> featb (dead after agg1)
  gemm_mfma_kernel<<<(NN + 63) / 64, 256, 0, stream>>>(aggb, Wb0, b0, pa, out_h, featb, hg);

  // layer 2
  agg_kernel<<<(NN + 3) / 4, 256, 0, stream>>>(featb, aggb, row_ptr, colx, norm_s, norm_d);
  gemm_mfma_kernel<<<(NN + 63) / 64, 256, 0, stream>>>(aggb, Wb1, b1, pa, out_h, (unsigned short*)nullptr, hg + 256);
}

// Round 3
// 473.916 us; speedup vs baseline: 1.7515x; 1.1718x over previous
//
#include <hip/hip_runtime.h>
#include <stdint.h>

#define NN 50000
#define NE 800000
#define DIM 256

typedef __bf16 bf16x8 __attribute__((ext_vector_type(8)));
typedef float f32x4 __attribute__((ext_vector_type(4)));

__device__ __forceinline__ unsigned short f2bf(float f) {
  union { float f; unsigned u; } v; v.f = f;
  unsigned r = v.u + 0x7fffu + ((v.u >> 16) & 1u);
  return (unsigned short)(r >> 16);
}
__device__ __forceinline__ float bf2f(unsigned short h) {
  union { unsigned u; float f; } v; v.u = ((unsigned)h) << 16;
  return v.f;
}

// ---------------- degree histogram ----------------
__global__ void deg_kernel(const int* __restrict__ src, const int* __restrict__ dst,
                           int* __restrict__ out_cnt, int* __restrict__ in_cnt) {
  int e = blockIdx.x * blockDim.x + threadIdx.x;
  if (e < NE) {
    atomicAdd(&out_cnt[src[e]], 1);
    atomicAdd(&in_cnt[dst[e]], 1);
  }
}

// ---------------- norms ----------------
__global__ void norm_kernel(const int* __restrict__ out_cnt, const int* __restrict__ in_cnt,
                            float* __restrict__ norm_s, float* __restrict__ norm_d) {
  int i = blockIdx.x * blockDim.x + threadIdx.x;
  if (i < NN) {
    norm_s[i] = rsqrtf(fmaxf((float)out_cnt[i], 1.0f));
    norm_d[i] = rsqrtf(fmaxf((float)in_cnt[i], 1.0f));
  }
}

// ---------------- exclusive scan (single block) ----------------
__global__ __launch_bounds__(1024) void scan_kernel(const int* __restrict__ in_cnt,
                                                    int* __restrict__ row_ptr,
                                                    int* __restrict__ cursor) {
  __shared__ int wsum[16];
  int tid = threadIdx.x;
  int lane = tid & 63, wave = tid >> 6;
  int carry = 0;
  for (int base = 0; base < NN; base += 4096) {
    int i0 = base + tid * 4;
    int v[4];
#pragma unroll
    for (int j = 0; j < 4; ++j) {
      int i = i0 + j;
      v[j] = (i < NN) ? in_cnt[i] : 0;
    }
    int tsum = v[0] + v[1] + v[2] + v[3];
    int incl = tsum;
#pragma unroll
    for (int off = 1; off < 64; off <<= 1) {
      int t = __shfl_up(incl, off, 64);
      if (lane >= off) incl += t;
    }
    if (lane == 63) wsum[wave] = incl;
    __syncthreads();
    int waveoff = 0;
    for (int w = 0; w < wave; ++w) waveoff += wsum[w];
    int chunk_total = 0;
    for (int w = 0; w < 16; ++w) chunk_total += wsum[w];
    int run = carry + waveoff + (incl - tsum);
#pragma unroll
    for (int j = 0; j < 4; ++j) {
      int i = i0 + j;
      if (i < NN) { row_ptr[i] = run; cursor[i] = run; }
      run += v[j];
    }
    carry += chunk_total;
    __syncthreads();
  }
  if (tid == 0) row_ptr[NN] = carry;
}

// ---------------- CSR fill ----------------
__global__ void fill_kernel(const int* __restrict__ src, const int* __restrict__ dst,
                            int* __restrict__ cursor, int* __restrict__ colx) {
  int e = blockIdx.x * blockDim.x + threadIdx.x;
  if (e < NE) {
    int p = atomicAdd(&cursor[dst[e]], 1);
    colx[p] = src[e];
  }
}

// ---------------- f32 -> bf16 cast with per-row norm_s scaling ----------------
// thread handles 4 elems; 64 threads per row
__global__ void cast_scale_kernel(const float* __restrict__ in, const float* __restrict__ norm_s,
                                  unsigned short* __restrict__ out, int n4) {
  int i = blockIdx.x * blockDim.x + threadIdx.x;
  if (i < n4) {
    float s = norm_s[i >> 6];
    float4 v = ((const float4*)in)[i];
    ushort4 o;
    o.x = f2bf(v.x * s); o.y = f2bf(v.y * s); o.z = f2bf(v.z * s); o.w = f2bf(v.w * s);
    ((ushort4*)out)[i] = o;
  }
}

// ---------------- W (256x256 f32 row-major, K x N) -> MFMA B-frag swizzled bf16 ----------------
__global__ void swizzleW_kernel(const float* __restrict__ W, unsigned short* __restrict__ Wb) {
  int idx = blockIdx.x * blockDim.x + threadIdx.x;  // 0 .. 8191
  if (idx >= 16 * 8 * 64) return;
  int lane = idx & 63;
  int blk = idx >> 6;
  int kc = blk & 7, nt = blk >> 3;
  int kbase = kc * 32 + (lane >> 4) * 8;
  int col = nt * 16 + (lane & 15);
  ushort4 o0, o1;
  o0.x = f2bf(W[(size_t)(kbase + 0) * DIM + col]);
  o0.y = f2bf(W[(size_t)(kbase + 1) * DIM + col]);
  o0.z = f2bf(W[(size_t)(kbase + 2) * DIM + col]);
  o0.w = f2bf(W[(size_t)(kbase + 3) * DIM + col]);
  o1.x = f2bf(W[(size_t)(kbase + 4) * DIM + col]);
  o1.y = f2bf(W[(size_t)(kbase + 5) * DIM + col]);
  o1.z = f2bf(W[(size_t)(kbase + 6) * DIM + col]);
  o1.w = f2bf(W[(size_t)(kbase + 7) * DIM + col]);
  ((ushort4*)Wb)[idx * 2 + 0] = o0;
  ((ushort4*)Wb)[idx * 2 + 1] = o1;
}

// ---------------- gather-aggregate (X pre-scaled by norm_s): agg[n] = nd[n]*sum X[c] ----------------
// wave per node; half-waves process even/odd edges; 16B/lane (8 bf16 dims)
__device__ __forceinline__ void acc_row(float* a, uint4 p) {
  a[0] += __uint_as_float(p.x << 16);
  a[1] += __uint_as_float(p.x & 0xffff0000u);
  a[2] += __uint_as_float(p.y << 16);
  a[3] += __uint_as_float(p.y & 0xffff0000u);
  a[4] += __uint_as_float(p.z << 16);
  a[5] += __uint_as_float(p.z & 0xffff0000u);
  a[6] += __uint_as_float(p.w << 16);
  a[7] += __uint_as_float(p.w & 0xffff0000u);
}

__global__ __launch_bounds__(256) void agg_kernel(const unsigned short* __restrict__ X,
                                                  unsigned short* __restrict__ agg,
                                                  const int* __restrict__ row_ptr,
                                                  const int* __restrict__ colx,
                                                  const float* __restrict__ norm_d) {
  int wave = threadIdx.x >> 6;
  int lane = threadIdx.x & 63;
  int half = lane >> 5;     // 0 or 1
  int sl = lane & 31;       // 16B segment within the 512B row
  int node = blockIdx.x * 4 + wave;
  if (node >= NN) return;
  int beg = row_ptr[node];
  int end = row_ptr[node + 1];

  float a[8];
#pragma unroll
  for (int j = 0; j < 8; ++j) a[j] = 0.f;

  int i = beg;
  // main: 4 edges per iteration (2 per half-wave), 2 rows in flight per lane
  for (; i + 4 <= end; i += 4) {
    int c0 = colx[i + half];
    int c1 = colx[i + 2 + half];
    uint4 r0 = *(const uint4*)(X + (size_t)c0 * DIM + sl * 8);
    uint4 r1 = *(const uint4*)(X + (size_t)c1 * DIM + sl * 8);
    acc_row(a, r0);
    acc_row(a, r1);
  }
  // remainder pair
  if (i + 2 <= end) {
    int c = colx[i + half];
    uint4 r = *(const uint4*)(X + (size_t)c * DIM + sl * 8);
    acc_row(a, r);
    i += 2;
  }
  // last single edge (lo half only)
  if (i < end && half == 0) {
    int c = colx[i];
    uint4 r = *(const uint4*)(X + (size_t)c * DIM + sl * 8);
    acc_row(a, r);
  }
  // combine halves
#pragma unroll
  for (int j = 0; j < 8; ++j) a[j] += __shfl_xor(a[j], 32, 64);

  if (half == 0) {
    float nd = norm_d[node];
    uint4 o;
    o.x = (unsigned)f2bf(a[0] * nd) | ((unsigned)f2bf(a[1] * nd) << 16);
    o.y = (unsigned)f2bf(a[2] * nd) | ((unsigned)f2bf(a[3] * nd) << 16);
    o.z = (unsigned)f2bf(a[4] * nd) | ((unsigned)f2bf(a[5] * nd) << 16);
    o.w = (unsigned)f2bf(a[6] * nd) | ((unsigned)f2bf(a[7] * nd) << 16);
    *(uint4*)(agg + (size_t)node * DIM + sl * 8) = o;
  }
}

// ---------------- MFMA GEMM + bias + PReLU + (scaled bf16 copy) + column-sum pooling ----------------
#define LDSROW 264  // 256 + 8 bf16 pad
__global__ __launch_bounds__(256) void gemm_mfma_kernel(const unsigned short* __restrict__ A,
                                                        const unsigned short* __restrict__ Wb,
                                                        const float* __restrict__ bias,
                                                        const float* __restrict__ prelu_a_ptr,
                                                        const float* __restrict__ norm_s,
                                                        float* __restrict__ C,
                                                        unsigned short* __restrict__ Cb,
                                                        float* __restrict__ hg) {
  __shared__ unsigned short As[64 * LDSROW];
  int tid = threadIdx.x;
  int r0 = blockIdx.x * 64;
#pragma unroll
  for (int p = 0; p < 8; ++p) {
    int idx = p * 256 + tid;
    int row = idx >> 5;
    int seg = idx & 31;
    int grow = r0 + row;
    ushort4 v0 = {0, 0, 0, 0}, v1 = {0, 0, 0, 0};
    if (grow < NN) {
      const ushort4* g = (const ushort4*)(A + (size_t)grow * DIM + seg * 8);
      v0 = g[0]; v1 = g[1];
    }
    *(ushort4*)(&As[row * LDSROW + seg * 8 + 0]) = v0;
    *(ushort4*)(&As[row * LDSROW + seg * 8 + 4]) = v1;
  }
  __syncthreads();

  int wave = tid >> 6, lane = tid & 63;
  int quad = lane >> 4, l16 = lane & 15;

  f32x4 acc[4][4];
#pragma unroll
  for (int mt = 0; mt < 4; ++mt)
#pragma unroll
    for (int nti = 0; nti < 4; ++nti)
      acc[mt][nti] = (f32x4){0.f, 0.f, 0.f, 0.f};

#pragma unroll
  for (int kc = 0; kc < 8; ++kc) {
    bf16x8 a[4], b[4];
#pragma unroll
    for (int mt = 0; mt < 4; ++mt)
      a[mt] = *(const bf16x8*)(&As[(mt * 16 + l16) * LDSROW + kc * 32 + quad * 8]);
#pragma unroll
    for (int nti = 0; nti < 4; ++nti) {
      int nt = wave * 4 + nti;
      b[nti] = *(const bf16x8*)(Wb + ((size_t)(nt * 8 + kc) * 64 + lane) * 8);
    }
#pragma unroll
    for (int mt = 0; mt < 4; ++mt)
#pragma unroll
      for (int nti = 0; nti < 4; ++nti)
        acc[mt][nti] = __builtin_amdgcn_mfma_f32_16x16x32_bf16(a[mt], b[nti], acc[mt][nti], 0, 0, 0);
  }

  float pa = *prelu_a_ptr;
  float bv[4], cs[4];
#pragma unroll
  for (int nti = 0; nti < 4; ++nti) {
    bv[nti] = bias[wave * 64 + nti * 16 + l16];
    cs[nti] = 0.f;
  }

#pragma unroll
  for (int mt = 0; mt < 4; ++mt) {
    float nsr[4] = {0.f, 0.f, 0.f, 0.f};
    if (Cb) {
#pragma unroll
      for (int r = 0; r < 4; ++r) {
        int rowg = r0 + mt * 16 + quad * 4 + r;
        if (rowg < NN) nsr[r] = norm_s[rowg];
      }
    }
#pragma unroll
    for (int nti = 0; nti < 4; ++nti) {
      int colg = wave * 64 + nti * 16 + l16;
#pragma unroll
      for (int r = 0; r < 4; ++r) {
        int rowg = r0 + mt * 16 + quad * 4 + r;
        if (rowg < NN) {
          float x = acc[mt][nti][r] + bv[nti];
          x = (x >= 0.f) ? x : pa * x;
          C[(size_t)rowg * DIM + colg] = x;
          if (Cb) Cb[(size_t)rowg * DIM + colg] = f2bf(x * nsr[r]);
          cs[nti] += x;
        }
      }
    }
  }
#pragma unroll
  for (int nti = 0; nti < 4; ++nti) {
    cs[nti] += __shfl_xor(cs[nti], 16, 64);
    cs[nti] += __shfl_xor(cs[nti], 32, 64);
  }
  if (quad == 0) {
#pragma unroll
    for (int nti = 0; nti < 4; ++nti)
      atomicAdd(&hg[wave * 64 + nti * 16 + l16], cs[nti]);
  }
}

extern "C" void kernel_launch(void* const* d_in, const int* in_sizes, int n_in,
                              void* d_out, int out_size, void* d_ws, size_t ws_size,
                              hipStream_t stream) {
  const float* feat = (const float*)d_in[0];
  const int* src    = (const int*)d_in[1];
  const int* dst    = (const int*)d_in[2];
  const float* W0   = (const float*)d_in[3];
  const float* b0   = (const float*)d_in[4];
  const float* W1   = (const float*)d_in[5];
  const float* b1   = (const float*)d_in[6];
  const float* pa   = (const float*)d_in[7];

  float* out_h = (float*)d_out;                      // [NN, DIM] f32
  float* hg    = out_h + (size_t)NN * DIM;           // [512] f32

  char* w = (char*)d_ws;
  int* out_cnt  = (int*)w;        w += (size_t)NN * 4;
  int* in_cnt   = (int*)w;        w += (size_t)NN * 4;
  float* norm_s = (float*)w;      w += (size_t)NN * 4;
  float* norm_d = (float*)w;      w += (size_t)NN * 4;
  int* row_ptr  = (int*)w;        w += (size_t)(NN + 1) * 4;
  int* cursor   = (int*)w;        w += (size_t)NN * 4;
  int* colx     = (int*)w;        w += (size_t)NE * 4;
  unsigned short* Wb0 = (unsigned short*)w;  w += (size_t)DIM * DIM * 2;
  unsigned short* Wb1 = (unsigned short*)w;  w += (size_t)DIM * DIM * 2;
  uintptr_t ap = ((uintptr_t)w + 255) & ~(uintptr_t)255;
  unsigned short* featb = (unsigned short*)ap;                 // [NN,DIM] bf16 (pre-scaled; reused as h1b)
  unsigned short* aggb  = featb + (size_t)NN * DIM;            // [NN,DIM] bf16

  hipMemsetAsync(out_cnt, 0, (size_t)NN * 2 * sizeof(int), stream);
  hipMemsetAsync(hg, 0, 512 * sizeof(float), stream);

  deg_kernel<<<(NE + 255) / 256, 256, 0, stream>>>(src, dst, out_cnt, in_cnt);
  norm_kernel<<<(NN + 255) / 256, 256, 0, stream>>>(out_cnt, in_cnt, norm_s, norm_d);
  scan_kernel<<<1, 1024, 0, stream>>>(in_cnt, row_ptr, cursor);
  fill_kernel<<<(NE + 255) / 256, 256, 0, stream>>>(src, dst, cursor, colx);

  cast_scale_kernel<<<(NN * DIM / 4 + 255) / 256, 256, 0, stream>>>(feat, norm_s, featb, NN * DIM / 4);
  swizzleW_kernel<<<32, 256, 0, stream>>>(W0, Wb0);
  swizzleW_kernel<<<32, 256, 0, stream>>>(W1, Wb1);

  // layer 1
  agg_kernel<<<(NN + 3) / 4, 256, 0, stream>>>(featb, aggb, row_ptr, colx, norm_d);
  // h1 f32 -> out_h (overwritten by layer 2), h1*norm_s bf16 -> featb (dead after agg1)
  gemm_mfma_kernel<<<(NN + 63) / 64, 256, 0, stream>>>(aggb, Wb0, b0, pa, norm_s, out_h, featb, hg);

  // layer 2
  agg_kernel<<<(NN + 3) / 4, 256, 0, stream>>>(featb, aggb, row_ptr, colx, norm_d);
  gemm_mfma_kernel<<<(NN + 63) / 64, 256, 0, stream>>>(aggb, Wb1, b1, pa, norm_s, out_h, (unsigned short*)nullptr, hg + 256);
}

// Round 4
// 430.174 us; speedup vs baseline: 1.9296x; 1.1017x over previous
//
#include <hip/hip_runtime.h>
#include <stdint.h>

#define NN 50000
#define NE 800000
#define DIM 256

// hist privatization params
#define HB 128     // hist blocks
#define HT 512     // hist threads/block
#define HALF 25000 // nodes per range (2 ranges cover NN)
#define HWORDS 12500 // packed words per range (2 nodes/word)

typedef __bf16 bf16x8 __attribute__((ext_vector_type(8)));
typedef float f32x4 __attribute__((ext_vector_type(4)));

__device__ __forceinline__ unsigned short f2bf(float f) {
  union { float f; unsigned u; } v; v.f = f;
  unsigned r = v.u + 0x7fffu + ((v.u >> 16) & 1u);
  return (unsigned short)(r >> 16);
}
__device__ __forceinline__ float bf2f(unsigned short h) {
  union { unsigned u; float f; } v; v.u = ((unsigned)h) << 16;
  return v.f;
}

// ---------------- LDS-privatized degree histograms (no global atomics) ----------------
// 4 phases: {src,dst} x {range0,range1}. Packed 16-bit counters, 2 nodes/word.
__global__ __launch_bounds__(HT) void hist_kernel(const int* __restrict__ src,
                                                  const int* __restrict__ dst,
                                                  unsigned* __restrict__ Hs,
                                                  unsigned* __restrict__ Hd) {
  __shared__ unsigned lds[HWORDS];  // 50 KB
  const int tid = threadIdx.x;
  const int b = blockIdx.x;
#pragma unroll
  for (int phase = 0; phase < 4; ++phase) {
    const int* arr = (phase < 2) ? src : dst;
    unsigned* H = (phase < 2) ? Hs : Hd;
    const int r = phase & 1;
    const int lo = r * HALF;
    for (int w = tid; w < HWORDS; w += HT) lds[w] = 0u;
    __syncthreads();
    for (int e = b * HT + tid; e < NE; e += HB * HT) {
      unsigned local = (unsigned)(arr[e] - lo);
      if (local < (unsigned)HALF)
        atomicAdd(&lds[local >> 1], 1u << ((local & 1) * 16));
    }
    __syncthreads();
    for (int w = tid; w < HWORDS; w += HT)
      H[(size_t)b * HALF + r * HWORDS + w] = lds[w];
    __syncthreads();
  }
}

// ---------------- reduce per-block hists -> degrees + norms ----------------
__global__ void reduce_norm_kernel(const unsigned* __restrict__ Hs,
                                   const unsigned* __restrict__ Hd,
                                   int* __restrict__ in_cnt,
                                   float* __restrict__ norm_s,
                                   float* __restrict__ norm_d) {
  int n = blockIdx.x * blockDim.x + threadIdx.x;
  if (n >= NN) return;
  int r = (n >= HALF) ? 1 : 0;
  int local = n - r * HALF;
  int w = r * HWORDS + (local >> 1);
  int sh = (local & 1) * 16;
  unsigned ss = 0, dd = 0;  // packed sums; halves never overflow (true degree < 65536)
  for (int b = 0; b < HB; ++b) {
    ss += Hs[(size_t)b * HALF + w];
    dd += Hd[(size_t)b * HALF + w];
  }
  unsigned so = (ss >> sh) & 0xffffu;
  unsigned di = (dd >> sh) & 0xffffu;
  in_cnt[n] = (int)di;
  norm_s[n] = rsqrtf(fmaxf((float)so, 1.0f));
  norm_d[n] = rsqrtf(fmaxf((float)di, 1.0f));
}

// ---------------- exclusive scan (single block) ----------------
__global__ __launch_bounds__(1024) void scan_kernel(const int* __restrict__ in_cnt,
                                                    int* __restrict__ row_ptr,
                                                    int* __restrict__ cursor) {
  __shared__ int wsum[16];
  int tid = threadIdx.x;
  int lane = tid & 63, wave = tid >> 6;
  int carry = 0;
  for (int base = 0; base < NN; base += 4096) {
    int i0 = base + tid * 4;
    int v[4];
#pragma unroll
    for (int j = 0; j < 4; ++j) {
      int i = i0 + j;
      v[j] = (i < NN) ? in_cnt[i] : 0;
    }
    int tsum = v[0] + v[1] + v[2] + v[3];
    int incl = tsum;
#pragma unroll
    for (int off = 1; off < 64; off <<= 1) {
      int t = __shfl_up(incl, off, 64);
      if (lane >= off) incl += t;
    }
    if (lane == 63) wsum[wave] = incl;
    __syncthreads();
    int waveoff = 0;
    for (int w = 0; w < wave; ++w) waveoff += wsum[w];
    int chunk_total = 0;
    for (int w = 0; w < 16; ++w) chunk_total += wsum[w];
    int run = carry + waveoff + (incl - tsum);
#pragma unroll
    for (int j = 0; j < 4; ++j) {
      int i = i0 + j;
      if (i < NN) { row_ptr[i] = run; cursor[i] = run; }
      run += v[j];
    }
    carry += chunk_total;
    __syncthreads();
  }
  if (tid == 0) row_ptr[NN] = carry;
}

// ---------------- CSR fill ----------------
__global__ void fill_kernel(const int* __restrict__ src, const int* __restrict__ dst,
                            int* __restrict__ cursor, int* __restrict__ colx) {
  int e = blockIdx.x * blockDim.x + threadIdx.x;
  if (e < NE) {
    int p = atomicAdd(&cursor[dst[e]], 1);
    colx[p] = src[e];
  }
}

// ---------------- f32 -> bf16 cast with per-row norm_s scaling ----------------
__global__ void cast_scale_kernel(const float* __restrict__ in, const float* __restrict__ norm_s,
                                  unsigned short* __restrict__ out, int n4) {
  int i = blockIdx.x * blockDim.x + threadIdx.x;
  if (i < n4) {
    float s = norm_s[i >> 6];
    float4 v = ((const float4*)in)[i];
    ushort4 o;
    o.x = f2bf(v.x * s); o.y = f2bf(v.y * s); o.z = f2bf(v.z * s); o.w = f2bf(v.w * s);
    ((ushort4*)out)[i] = o;
  }
}

// ---------------- W (256x256 f32 row-major, K x N) -> MFMA B-frag swizzled bf16 ----------------
__global__ void swizzleW_kernel(const float* __restrict__ W, unsigned short* __restrict__ Wb) {
  int idx = blockIdx.x * blockDim.x + threadIdx.x;  // 0 .. 8191
  if (idx >= 16 * 8 * 64) return;
  int lane = idx & 63;
  int blk = idx >> 6;
  int kc = blk & 7, nt = blk >> 3;
  int kbase = kc * 32 + (lane >> 4) * 8;
  int col = nt * 16 + (lane & 15);
  ushort4 o0, o1;
  o0.x = f2bf(W[(size_t)(kbase + 0) * DIM + col]);
  o0.y = f2bf(W[(size_t)(kbase + 1) * DIM + col]);
  o0.z = f2bf(W[(size_t)(kbase + 2) * DIM + col]);
  o0.w = f2bf(W[(size_t)(kbase + 3) * DIM + col]);
  o1.x = f2bf(W[(size_t)(kbase + 4) * DIM + col]);
  o1.y = f2bf(W[(size_t)(kbase + 5) * DIM + col]);
  o1.z = f2bf(W[(size_t)(kbase + 6) * DIM + col]);
  o1.w = f2bf(W[(size_t)(kbase + 7) * DIM + col]);
  ((ushort4*)Wb)[idx * 2 + 0] = o0;
  ((ushort4*)Wb)[idx * 2 + 1] = o1;
}

// ---------------- gather-aggregate (X pre-scaled by norm_s): agg[n] = nd[n]*sum X[c] ----------------
__device__ __forceinline__ void acc_row(float* a, uint4 p) {
  a[0] += __uint_as_float(p.x << 16);
  a[1] += __uint_as_float(p.x & 0xffff0000u);
  a[2] += __uint_as_float(p.y << 16);
  a[3] += __uint_as_float(p.y & 0xffff0000u);
  a[4] += __uint_as_float(p.z << 16);
  a[5] += __uint_as_float(p.z & 0xffff0000u);
  a[6] += __uint_as_float(p.w << 16);
  a[7] += __uint_as_float(p.w & 0xffff0000u);
}

__global__ __launch_bounds__(256) void agg_kernel(const unsigned short* __restrict__ X,
                                                  unsigned short* __restrict__ agg,
                                                  const int* __restrict__ row_ptr,
                                                  const int* __restrict__ colx,
                                                  const float* __restrict__ norm_d) {
  int wave = threadIdx.x >> 6;
  int lane = threadIdx.x & 63;
  int half = lane >> 5;
  int sl = lane & 31;
  int node = blockIdx.x * 4 + wave;
  if (node >= NN) return;
  int beg = row_ptr[node];
  int end = row_ptr[node + 1];

  float a[8];
#pragma unroll
  for (int j = 0; j < 8; ++j) a[j] = 0.f;

  int i = beg;
  for (; i + 4 <= end; i += 4) {
    int c0 = colx[i + half];
    int c1 = colx[i + 2 + half];
    uint4 r0 = *(const uint4*)(X + (size_t)c0 * DIM + sl * 8);
    uint4 r1 = *(const uint4*)(X + (size_t)c1 * DIM + sl * 8);
    acc_row(a, r0);
    acc_row(a, r1);
  }
  if (i + 2 <= end) {
    int c = colx[i + half];
    uint4 r = *(const uint4*)(X + (size_t)c * DIM + sl * 8);
    acc_row(a, r);
    i += 2;
  }
  if (i < end && half == 0) {
    int c = colx[i];
    uint4 r = *(const uint4*)(X + (size_t)c * DIM + sl * 8);
    acc_row(a, r);
  }
#pragma unroll
  for (int j = 0; j < 8; ++j) a[j] += __shfl_xor(a[j], 32, 64);

  if (half == 0) {
    float nd = norm_d[node];
    uint4 o;
    o.x = (unsigned)f2bf(a[0] * nd) | ((unsigned)f2bf(a[1] * nd) << 16);
    o.y = (unsigned)f2bf(a[2] * nd) | ((unsigned)f2bf(a[3] * nd) << 16);
    o.z = (unsigned)f2bf(a[4] * nd) | ((unsigned)f2bf(a[5] * nd) << 16);
    o.w = (unsigned)f2bf(a[6] * nd) | ((unsigned)f2bf(a[7] * nd) << 16);
    *(uint4*)(agg + (size_t)node * DIM + sl * 8) = o;
  }
}

// ---------------- MFMA GEMM + bias + PReLU + (scaled bf16 copy) + column-sum pooling ----------------
#define LDSROW 264
__global__ __launch_bounds__(256) void gemm_mfma_kernel(const unsigned short* __restrict__ A,
                                                        const unsigned short* __restrict__ Wb,
                                                        const float* __restrict__ bias,
                                                        const float* __restrict__ prelu_a_ptr,
                                                        const float* __restrict__ norm_s,
                                                        float* __restrict__ C,
                                                        unsigned short* __restrict__ Cb,
                                                        float* __restrict__ hg) {
  __shared__ unsigned short As[64 * LDSROW];
  int tid = threadIdx.x;
  int r0 = blockIdx.x * 64;
#pragma unroll
  for (int p = 0; p < 8; ++p) {
    int idx = p * 256 + tid;
    int row = idx >> 5;
    int seg = idx & 31;
    int grow = r0 + row;
    ushort4 v0 = {0, 0, 0, 0}, v1 = {0, 0, 0, 0};
    if (grow < NN) {
      const ushort4* g = (const ushort4*)(A + (size_t)grow * DIM + seg * 8);
      v0 = g[0]; v1 = g[1];
    }
    *(ushort4*)(&As[row * LDSROW + seg * 8 + 0]) = v0;
    *(ushort4*)(&As[row * LDSROW + seg * 8 + 4]) = v1;
  }
  __syncthreads();

  int wave = tid >> 6, lane = tid & 63;
  int quad = lane >> 4, l16 = lane & 15;

  f32x4 acc[4][4];
#pragma unroll
  for (int mt = 0; mt < 4; ++mt)
#pragma unroll
    for (int nti = 0; nti < 4; ++nti)
      acc[mt][nti] = (f32x4){0.f, 0.f, 0.f, 0.f};

#pragma unroll
  for (int kc = 0; kc < 8; ++kc) {
    bf16x8 a[4], b[4];
#pragma unroll
    for (int mt = 0; mt < 4; ++mt)
      a[mt] = *(const bf16x8*)(&As[(mt * 16 + l16) * LDSROW + kc * 32 + quad * 8]);
#pragma unroll
    for (int nti = 0; nti < 4; ++nti) {
      int nt = wave * 4 + nti;
      b[nti] = *(const bf16x8*)(Wb + ((size_t)(nt * 8 + kc) * 64 + lane) * 8);
    }
#pragma unroll
    for (int mt = 0; mt < 4; ++mt)
#pragma unroll
      for (int nti = 0; nti < 4; ++nti)
        acc[mt][nti] = __builtin_amdgcn_mfma_f32_16x16x32_bf16(a[mt], b[nti], acc[mt][nti], 0, 0, 0);
  }

  float pa = *prelu_a_ptr;
  float bv[4], cs[4];
#pragma unroll
  for (int nti = 0; nti < 4; ++nti) {
    bv[nti] = bias[wave * 64 + nti * 16 + l16];
    cs[nti] = 0.f;
  }

#pragma unroll
  for (int mt = 0; mt < 4; ++mt) {
    float nsr[4] = {0.f, 0.f, 0.f, 0.f};
    if (Cb) {
#pragma unroll
      for (int r = 0; r < 4; ++r) {
        int rowg = r0 + mt * 16 + quad * 4 + r;
        if (rowg < NN) nsr[r] = norm_s[rowg];
      }
    }
#pragma unroll
    for (int nti = 0; nti < 4; ++nti) {
      int colg = wave * 64 + nti * 16 + l16;
#pragma unroll
      for (int r = 0; r < 4; ++r) {
        int rowg = r0 + mt * 16 + quad * 4 + r;
        if (rowg < NN) {
          float x = acc[mt][nti][r] + bv[nti];
          x = (x >= 0.f) ? x : pa * x;
          C[(size_t)rowg * DIM + colg] = x;
          if (Cb) Cb[(size_t)rowg * DIM + colg] = f2bf(x * nsr[r]);
          cs[nti] += x;
        }
      }
    }
  }
#pragma unroll
  for (int nti = 0; nti < 4; ++nti) {
    cs[nti] += __shfl_xor(cs[nti], 16, 64);
    cs[nti] += __shfl_xor(cs[nti], 32, 64);
  }
  if (quad == 0) {
#pragma unroll
    for (int nti = 0; nti < 4; ++nti)
      atomicAdd(&hg[wave * 64 + nti * 16 + l16], cs[nti]);
  }
}

extern "C" void kernel_launch(void* const* d_in, const int* in_sizes, int n_in,
                              void* d_out, int out_size, void* d_ws, size_t ws_size,
                              hipStream_t stream) {
  const float* feat = (const float*)d_in[0];
  const int* src    = (const int*)d_in[1];
  const int* dst    = (const int*)d_in[2];
  const float* W0   = (const float*)d_in[3];
  const float* b0   = (const float*)d_in[4];
  const float* W1   = (const float*)d_in[5];
  const float* b1   = (const float*)d_in[6];
  const float* pa   = (const float*)d_in[7];

  float* out_h = (float*)d_out;                      // [NN, DIM] f32
  float* hg    = out_h + (size_t)NN * DIM;           // [512] f32

  char* w = (char*)d_ws;
  int* in_cnt   = (int*)w;        w += (size_t)NN * 4;
  float* norm_s = (float*)w;      w += (size_t)NN * 4;
  float* norm_d = (float*)w;      w += (size_t)NN * 4;
  int* row_ptr  = (int*)w;        w += (size_t)(NN + 1) * 4;
  int* cursor   = (int*)w;        w += (size_t)NN * 4;
  int* colx     = (int*)w;        w += (size_t)NE * 4;
  unsigned short* Wb0 = (unsigned short*)w;  w += (size_t)DIM * DIM * 2;
  unsigned short* Wb1 = (unsigned short*)w;  w += (size_t)DIM * DIM * 2;
  uintptr_t ap = ((uintptr_t)w + 255) & ~(uintptr_t)255;
  unsigned short* featb = (unsigned short*)ap;                 // [NN,DIM] bf16 (pre-scaled; reused as h1b)
  unsigned short* aggb  = featb + (size_t)NN * DIM;            // [NN,DIM] bf16
  // per-block histograms alias featb (25.6 MB) — dead before cast_scale writes featb
  unsigned* Hs = (unsigned*)ap;                  // [HB][25000 words] = 12.8 MB
  unsigned* Hd = Hs + (size_t)HB * HALF;         // [HB][25000 words] = 12.8 MB

  hipMemsetAsync(hg, 0, 512 * sizeof(float), stream);

  hist_kernel<<<HB, HT, 0, stream>>>(src, dst, Hs, Hd);
  reduce_norm_kernel<<<(NN + 255) / 256, 256, 0, stream>>>(Hs, Hd, in_cnt, norm_s, norm_d);
  scan_kernel<<<1, 1024, 0, stream>>>(in_cnt, row_ptr, cursor);
  fill_kernel<<<(NE + 255) / 256, 256, 0, stream>>>(src, dst, cursor, colx);

  cast_scale_kernel<<<(NN * DIM / 4 + 255) / 256, 256, 0, stream>>>(feat, norm_s, featb, NN * DIM / 4);
  swizzleW_kernel<<<32, 256, 0, stream>>>(W0, Wb0);
  swizzleW_kernel<<<32, 256, 0, stream>>>(W1, Wb1);

  // layer 1
  agg_kernel<<<(NN + 3) / 4, 256, 0, stream>>>(featb, aggb, row_ptr, colx, norm_d);
  gemm_mfma_kernel<<<(NN + 63) / 64, 256, 0, stream>>>(aggb, Wb0, b0, pa, norm_s, out_h, featb, hg);

  // layer 2
  agg_kernel<<<(NN + 3) / 4, 256, 0, stream>>>(featb, aggb, row_ptr, colx, norm_d);
  gemm_mfma_kernel<<<(NN + 63) / 64, 256, 0, stream>>>(aggb, Wb1, b1, pa, norm_s, out_h, (unsigned short*)nullptr, hg + 256);
}

// Round 5
// 423.081 us; speedup vs baseline: 1.9619x; 1.0168x over previous
//
#include <hip/hip_runtime.h>
#include <stdint.h>

#define NN 50000
#define NE 800000
#define DIM 256

// hist privatization params
#define HB 128     // hist blocks
#define HT 512     // hist threads/block
#define HALF 25000 // nodes per range (2 ranges cover NN)
#define HWORDS 12500 // packed words per range (2 nodes/word)

typedef __bf16 bf16x8 __attribute__((ext_vector_type(8)));
typedef float f32x4 __attribute__((ext_vector_type(4)));

__device__ __forceinline__ unsigned short f2bf(float f) {
  union { float f; unsigned u; } v; v.f = f;
  unsigned r = v.u + 0x7fffu + ((v.u >> 16) & 1u);
  return (unsigned short)(r >> 16);
}
__device__ __forceinline__ float bf2f(unsigned short h) {
  union { unsigned u; float f; } v; v.u = ((unsigned)h) << 16;
  return v.f;
}

// ---------------- LDS-privatized degree histograms (no global atomics) ----------------
__global__ __launch_bounds__(HT) void hist_kernel(const int* __restrict__ src,
                                                  const int* __restrict__ dst,
                                                  unsigned* __restrict__ Hs,
                                                  unsigned* __restrict__ Hd) {
  __shared__ unsigned lds[HWORDS];  // 50 KB
  const int tid = threadIdx.x;
  const int b = blockIdx.x;
#pragma unroll
  for (int phase = 0; phase < 4; ++phase) {
    const int* arr = (phase < 2) ? src : dst;
    unsigned* H = (phase < 2) ? Hs : Hd;
    const int r = phase & 1;
    const int lo = r * HALF;
    for (int w = tid; w < HWORDS; w += HT) lds[w] = 0u;
    __syncthreads();
    for (int e = b * HT + tid; e < NE; e += HB * HT) {
      unsigned local = (unsigned)(arr[e] - lo);
      if (local < (unsigned)HALF)
        atomicAdd(&lds[local >> 1], 1u << ((local & 1) * 16));
    }
    __syncthreads();
    for (int w = tid; w < HWORDS; w += HT)
      H[(size_t)b * HALF + r * HWORDS + w] = lds[w];
    __syncthreads();
  }
}

// ---------------- reduce per-block hists -> degrees + norms ----------------
__global__ void reduce_norm_kernel(const unsigned* __restrict__ Hs,
                                   const unsigned* __restrict__ Hd,
                                   int* __restrict__ in_cnt,
                                   float* __restrict__ norm_s,
                                   float* __restrict__ norm_d) {
  int n = blockIdx.x * blockDim.x + threadIdx.x;
  if (n >= NN) return;
  int r = (n >= HALF) ? 1 : 0;
  int local = n - r * HALF;
  int w = r * HWORDS + (local >> 1);
  int sh = (local & 1) * 16;
  unsigned ss = 0, dd = 0;
  for (int b = 0; b < HB; ++b) {
    ss += Hs[(size_t)b * HALF + w];
    dd += Hd[(size_t)b * HALF + w];
  }
  unsigned so = (ss >> sh) & 0xffffu;
  unsigned di = (dd >> sh) & 0xffffu;
  in_cnt[n] = (int)di;
  norm_s[n] = rsqrtf(fmaxf((float)so, 1.0f));
  norm_d[n] = rsqrtf(fmaxf((float)di, 1.0f));
}

// ---------------- exclusive scan (single block) ----------------
__global__ __launch_bounds__(1024) void scan_kernel(const int* __restrict__ in_cnt,
                                                    int* __restrict__ row_ptr,
                                                    int* __restrict__ cursor) {
  __shared__ int wsum[16];
  int tid = threadIdx.x;
  int lane = tid & 63, wave = tid >> 6;
  int carry = 0;
  for (int base = 0; base < NN; base += 4096) {
    int i0 = base + tid * 4;
    int v[4];
#pragma unroll
    for (int j = 0; j < 4; ++j) {
      int i = i0 + j;
      v[j] = (i < NN) ? in_cnt[i] : 0;
    }
    int tsum = v[0] + v[1] + v[2] + v[3];
    int incl = tsum;
#pragma unroll
    for (int off = 1; off < 64; off <<= 1) {
      int t = __shfl_up(incl, off, 64);
      if (lane >= off) incl += t;
    }
    if (lane == 63) wsum[wave] = incl;
    __syncthreads();
    int waveoff = 0;
    for (int w = 0; w < wave; ++w) waveoff += wsum[w];
    int chunk_total = 0;
    for (int w = 0; w < 16; ++w) chunk_total += wsum[w];
    int run = carry + waveoff + (incl - tsum);
#pragma unroll
    for (int j = 0; j < 4; ++j) {
      int i = i0 + j;
      if (i < NN) { row_ptr[i] = run; cursor[i] = run; }
      run += v[j];
    }
    carry += chunk_total;
    __syncthreads();
  }
  if (tid == 0) row_ptr[NN] = carry;
}

// ---------------- CSR fill ----------------
__global__ void fill_kernel(const int* __restrict__ src, const int* __restrict__ dst,
                            int* __restrict__ cursor, int* __restrict__ colx) {
  int e = blockIdx.x * blockDim.x + threadIdx.x;
  if (e < NE) {
    int p = atomicAdd(&cursor[dst[e]], 1);
    colx[p] = src[e];
  }
}

// ---------------- f32 -> bf16 cast with per-row norm_s scaling ----------------
__global__ void cast_scale_kernel(const float* __restrict__ in, const float* __restrict__ norm_s,
                                  unsigned short* __restrict__ out, int n4) {
  int i = blockIdx.x * blockDim.x + threadIdx.x;
  if (i < n4) {
    float s = norm_s[i >> 6];
    float4 v = ((const float4*)in)[i];
    ushort4 o;
    o.x = f2bf(v.x * s); o.y = f2bf(v.y * s); o.z = f2bf(v.z * s); o.w = f2bf(v.w * s);
    ((ushort4*)out)[i] = o;
  }
}

// ---------------- W (256x256 f32 row-major, K x N) -> MFMA B-frag swizzled bf16 ----------------
__global__ void swizzleW_kernel(const float* __restrict__ W, unsigned short* __restrict__ Wb) {
  int idx = blockIdx.x * blockDim.x + threadIdx.x;  // 0 .. 8191
  if (idx >= 16 * 8 * 64) return;
  int lane = idx & 63;
  int blk = idx >> 6;
  int kc = blk & 7, nt = blk >> 3;
  int kbase = kc * 32 + (lane >> 4) * 8;
  int col = nt * 16 + (lane & 15);
  ushort4 o0, o1;
  o0.x = f2bf(W[(size_t)(kbase + 0) * DIM + col]);
  o0.y = f2bf(W[(size_t)(kbase + 1) * DIM + col]);
  o0.z = f2bf(W[(size_t)(kbase + 2) * DIM + col]);
  o0.w = f2bf(W[(size_t)(kbase + 3) * DIM + col]);
  o1.x = f2bf(W[(size_t)(kbase + 4) * DIM + col]);
  o1.y = f2bf(W[(size_t)(kbase + 5) * DIM + col]);
  o1.z = f2bf(W[(size_t)(kbase + 6) * DIM + col]);
  o1.w = f2bf(W[(size_t)(kbase + 7) * DIM + col]);
  ((ushort4*)Wb)[idx * 2 + 0] = o0;
  ((ushort4*)Wb)[idx * 2 + 1] = o1;
}

// ---------------- gather-aggregate (X pre-scaled by norm_s): agg[n] = nd[n]*sum X[c] ----------------
__device__ __forceinline__ void acc_row(float* a, uint4 p) {
  a[0] += __uint_as_float(p.x << 16);
  a[1] += __uint_as_float(p.x & 0xffff0000u);
  a[2] += __uint_as_float(p.y << 16);
  a[3] += __uint_as_float(p.y & 0xffff0000u);
  a[4] += __uint_as_float(p.z << 16);
  a[5] += __uint_as_float(p.z & 0xffff0000u);
  a[6] += __uint_as_float(p.w << 16);
  a[7] += __uint_as_float(p.w & 0xffff0000u);
}

__global__ __launch_bounds__(256) void agg_kernel(const unsigned short* __restrict__ X,
                                                  unsigned short* __restrict__ agg,
                                                  const int* __restrict__ row_ptr,
                                                  const int* __restrict__ colx,
                                                  const float* __restrict__ norm_d) {
  int wave = threadIdx.x >> 6;
  int lane = threadIdx.x & 63;
  int half = lane >> 5;
  int sl = lane & 31;
  int node = blockIdx.x * 4 + wave;
  if (node >= NN) return;
  int beg = row_ptr[node];
  int end = row_ptr[node + 1];

  float a[8];
#pragma unroll
  for (int j = 0; j < 8; ++j) a[j] = 0.f;

  int i = beg;
  for (; i + 4 <= end; i += 4) {
    int c0 = colx[i + half];
    int c1 = colx[i + 2 + half];
    uint4 r0 = *(const uint4*)(X + (size_t)c0 * DIM + sl * 8);
    uint4 r1 = *(const uint4*)(X + (size_t)c1 * DIM + sl * 8);
    acc_row(a, r0);
    acc_row(a, r1);
  }
  if (i + 2 <= end) {
    int c = colx[i + half];
    uint4 r = *(const uint4*)(X + (size_t)c * DIM + sl * 8);
    acc_row(a, r);
    i += 2;
  }
  if (i < end && half == 0) {
    int c = colx[i];
    uint4 r = *(const uint4*)(X + (size_t)c * DIM + sl * 8);
    acc_row(a, r);
  }
#pragma unroll
  for (int j = 0; j < 8; ++j) a[j] += __shfl_xor(a[j], 32, 64);

  if (half == 0) {
    float nd = norm_d[node];
    uint4 o;
    o.x = (unsigned)f2bf(a[0] * nd) | ((unsigned)f2bf(a[1] * nd) << 16);
    o.y = (unsigned)f2bf(a[2] * nd) | ((unsigned)f2bf(a[3] * nd) << 16);
    o.z = (unsigned)f2bf(a[4] * nd) | ((unsigned)f2bf(a[5] * nd) << 16);
    o.w = (unsigned)f2bf(a[6] * nd) | ((unsigned)f2bf(a[7] * nd) << 16);
    *(uint4*)(agg + (size_t)node * DIM + sl * 8) = o;
  }
}

// ---------------- MFMA GEMM + bias + PReLU + coalesced epilogue + column-sum pooling ----------------
// Exactly one of C (f32 out) / Cb (norm_s-scaled bf16 out) is non-null.
#define LDSROW 264   // bf16 row stride for A tile
#define FROW 260     // f32 row stride for epilogue staging
__global__ __launch_bounds__(256) void gemm_mfma_kernel(const unsigned short* __restrict__ A,
                                                        const unsigned short* __restrict__ Wb,
                                                        const float* __restrict__ bias,
                                                        const float* __restrict__ prelu_a_ptr,
                                                        const float* __restrict__ norm_s,
                                                        float* __restrict__ C,
                                                        unsigned short* __restrict__ Cb,
                                                        float* __restrict__ hg) {
  __shared__ unsigned short As[64 * LDSROW];  // 33792 B; reused as f32 staging (needs 33280 B)
  int tid = threadIdx.x;
  int r0 = blockIdx.x * 64;
#pragma unroll
  for (int p = 0; p < 8; ++p) {
    int idx = p * 256 + tid;
    int row = idx >> 5;
    int seg = idx & 31;
    int grow = r0 + row;
    ushort4 v0 = {0, 0, 0, 0}, v1 = {0, 0, 0, 0};
    if (grow < NN) {
      const ushort4* g = (const ushort4*)(A + (size_t)grow * DIM + seg * 8);
      v0 = g[0]; v1 = g[1];
    }
    *(ushort4*)(&As[row * LDSROW + seg * 8 + 0]) = v0;
    *(ushort4*)(&As[row * LDSROW + seg * 8 + 4]) = v1;
  }
  __syncthreads();

  int wave = tid >> 6, lane = tid & 63;
  int quad = lane >> 4, l16 = lane & 15;

  f32x4 acc[4][4];
#pragma unroll
  for (int mt = 0; mt < 4; ++mt)
#pragma unroll
    for (int nti = 0; nti < 4; ++nti)
      acc[mt][nti] = (f32x4){0.f, 0.f, 0.f, 0.f};

#pragma unroll
  for (int kc = 0; kc < 8; ++kc) {
    bf16x8 a[4], b[4];
#pragma unroll
    for (int mt = 0; mt < 4; ++mt)
      a[mt] = *(const bf16x8*)(&As[(mt * 16 + l16) * LDSROW + kc * 32 + quad * 8]);
#pragma unroll
    for (int nti = 0; nti < 4; ++nti) {
      int nt = wave * 4 + nti;
      b[nti] = *(const bf16x8*)(Wb + ((size_t)(nt * 8 + kc) * 64 + lane) * 8);
    }
#pragma unroll
    for (int mt = 0; mt < 4; ++mt)
#pragma unroll
      for (int nti = 0; nti < 4; ++nti)
        acc[mt][nti] = __builtin_amdgcn_mfma_f32_16x16x32_bf16(a[mt], b[nti], acc[mt][nti], 0, 0, 0);
  }

  // bias + PReLU + column sums, in registers (MFMA C-layout: col=l16, row=quad*4+r)
  float pa = *prelu_a_ptr;
  float bv[4], cs[4];
#pragma unroll
  for (int nti = 0; nti < 4; ++nti) {
    bv[nti] = bias[wave * 64 + nti * 16 + l16];
    cs[nti] = 0.f;
  }
#pragma unroll
  for (int mt = 0; mt < 4; ++mt) {
#pragma unroll
    for (int nti = 0; nti < 4; ++nti) {
#pragma unroll
      for (int r = 0; r < 4; ++r) {
        int rowg = r0 + mt * 16 + quad * 4 + r;
        float x = acc[mt][nti][r] + bv[nti];
        x = (x >= 0.f) ? x : pa * x;
        acc[mt][nti][r] = x;
        if (rowg < NN) cs[nti] += x;
      }
    }
  }
#pragma unroll
  for (int nti = 0; nti < 4; ++nti) {
    cs[nti] += __shfl_xor(cs[nti], 16, 64);
    cs[nti] += __shfl_xor(cs[nti], 32, 64);
  }
  if (quad == 0) {
#pragma unroll
    for (int nti = 0; nti < 4; ++nti)
      atomicAdd(&hg[wave * 64 + nti * 16 + l16], cs[nti]);
  }

  // coalesced store epilogue: stage 32-row half-tiles through LDS
  float* LF = (float*)As;  // [32][FROW]
#pragma unroll
  for (int chunk = 0; chunk < 2; ++chunk) {
    __syncthreads();
#pragma unroll
    for (int mi = 0; mi < 2; ++mi) {
      int mt = chunk * 2 + mi;
#pragma unroll
      for (int nti = 0; nti < 4; ++nti) {
        int colw = wave * 64 + nti * 16 + l16;
#pragma unroll
        for (int r = 0; r < 4; ++r)
          LF[(mi * 16 + quad * 4 + r) * FROW + colw] = acc[mt][nti][r];
      }
    }
    __syncthreads();
    int rowbase = r0 + chunk * 32;
    if (C) {
#pragma unroll
      for (int s = 0; s < 8; ++s) {
        int g = s * 256 + tid;
        int row = g >> 6, cg = g & 63;
        int rowg = rowbase + row;
        if (rowg < NN) {
          float4 v = *(const float4*)&LF[row * FROW + cg * 4];
          *(float4*)(C + (size_t)rowg * DIM + cg * 4) = v;
        }
      }
    }
    if (Cb) {
#pragma unroll
      for (int s = 0; s < 4; ++s) {
        int g = s * 256 + tid;
        int row = g >> 5, cg = g & 31;
        int rowg = rowbase + row;
        if (rowg < NN) {
          float ns = norm_s[rowg];
          float4 v0 = *(const float4*)&LF[row * FROW + cg * 8];
          float4 v1 = *(const float4*)&LF[row * FROW + cg * 8 + 4];
          uint4 o;
          o.x = (unsigned)f2bf(v0.x * ns) | ((unsigned)f2bf(v0.y * ns) << 16);
          o.y = (unsigned)f2bf(v0.z * ns) | ((unsigned)f2bf(v0.w * ns) << 16);
          o.z = (unsigned)f2bf(v1.x * ns) | ((unsigned)f2bf(v1.y * ns) << 16);
          o.w = (unsigned)f2bf(v1.z * ns) | ((unsigned)f2bf(v1.w * ns) << 16);
          *(uint4*)(Cb + (size_t)rowg * DIM + cg * 8) = o;
        }
      }
    }
  }
}

extern "C" void kernel_launch(void* const* d_in, const int* in_sizes, int n_in,
                              void* d_out, int out_size, void* d_ws, size_t ws_size,
                              hipStream_t stream) {
  const float* feat = (const float*)d_in[0];
  const int* src    = (const int*)d_in[1];
  const int* dst    = (const int*)d_in[2];
  const float* W0   = (const float*)d_in[3];
  const float* b0   = (const float*)d_in[4];
  const float* W1   = (const float*)d_in[5];
  const float* b1   = (const float*)d_in[6];
  const float* pa   = (const float*)d_in[7];

  float* out_h = (float*)d_out;                      // [NN, DIM] f32
  float* hg    = out_h + (size_t)NN * DIM;           // [512] f32

  char* w = (char*)d_ws;
  int* in_cnt   = (int*)w;        w += (size_t)NN * 4;
  float* norm_s = (float*)w;      w += (size_t)NN * 4;
  float* norm_d = (float*)w;      w += (size_t)NN * 4;
  int* row_ptr  = (int*)w;        w += (size_t)(NN + 1) * 4;
  int* cursor   = (int*)w;        w += (size_t)NN * 4;
  int* colx     = (int*)w;        w += (size_t)NE * 4;
  unsigned short* Wb0 = (unsigned short*)w;  w += (size_t)DIM * DIM * 2;
  unsigned short* Wb1 = (unsigned short*)w;  w += (size_t)DIM * DIM * 2;
  uintptr_t ap = ((uintptr_t)w + 255) & ~(uintptr_t)255;
  unsigned short* featb = (unsigned short*)ap;                 // [NN,DIM] bf16 (pre-scaled; reused as h1b)
  unsigned short* aggb  = featb + (size_t)NN * DIM;            // [NN,DIM] bf16
  // per-block histograms alias featb (25.6 MB) — dead before cast_scale writes featb
  unsigned* Hs = (unsigned*)ap;                  // [HB][25000 words] = 12.8 MB
  unsigned* Hd = Hs + (size_t)HB * HALF;         // [HB][25000 words] = 12.8 MB

  hipMemsetAsync(hg, 0, 512 * sizeof(float), stream);

  hist_kernel<<<HB, HT, 0, stream>>>(src, dst, Hs, Hd);
  reduce_norm_kernel<<<(NN + 255) / 256, 256, 0, stream>>>(Hs, Hd, in_cnt, norm_s, norm_d);
  scan_kernel<<<1, 1024, 0, stream>>>(in_cnt, row_ptr, cursor);
  fill_kernel<<<(NE + 255) / 256, 256, 0, stream>>>(src, dst, cursor, colx);

  cast_scale_kernel<<<(NN * DIM / 4 + 255) / 256, 256, 0, stream>>>(feat, norm_s, featb, NN * DIM / 4);
  swizzleW_kernel<<<32, 256, 0, stream>>>(W0, Wb0);
  swizzleW_kernel<<<32, 256, 0, stream>>>(W1, Wb1);

  // layer 1: only the scaled-bf16 h1 is live (f32 h1 was a dead write)
  agg_kernel<<<(NN + 3) / 4, 256, 0, stream>>>(featb, aggb, row_ptr, colx, norm_d);
  gemm_mfma_kernel<<<(NN + 63) / 64, 256, 0, stream>>>(aggb, Wb0, b0, pa, norm_s,
                                                       (float*)nullptr, featb, hg);

  // layer 2: f32 output only
  agg_kernel<<<(NN + 3) / 4, 256, 0, stream>>>(featb, aggb, row_ptr, colx, norm_d);
  gemm_mfma_kernel<<<(NN + 63) / 64, 256, 0, stream>>>(aggb, Wb1, b1, pa, norm_s,
                                                       out_h, (unsigned short*)nullptr, hg + 256);
}

// Round 6
// 413.032 us; speedup vs baseline: 2.0097x; 1.0243x over previous
//
#include <hip/hip_runtime.h>
#include <stdint.h>

#define NN 50000
#define NE 800000
#define DIM 256

// hist privatization params
#define HB 128      // hist blocks
#define HT 512      // hist threads/block
#define HALF 25000  // nodes per range (2 ranges cover NN); also words-per-block stride
#define HWORDS 12500 // packed words per range (2 nodes/word)

typedef __bf16 bf16x8 __attribute__((ext_vector_type(8)));
typedef float f32x4 __attribute__((ext_vector_type(4)));

__device__ __forceinline__ unsigned short f2bf(float f) {
  union { float f; unsigned u; } v; v.f = f;
  unsigned r = v.u + 0x7fffu + ((v.u >> 16) & 1u);
  return (unsigned short)(r >> 16);
}

// ---------------- LDS-privatized degree histograms (no global atomics) ----------------
__global__ __launch_bounds__(HT) void hist_kernel(const int* __restrict__ src,
                                                  const int* __restrict__ dst,
                                                  unsigned* __restrict__ Hs,
                                                  unsigned* __restrict__ Hd) {
  __shared__ unsigned lds[HWORDS];  // 50 KB
  const int tid = threadIdx.x;
  const int b = blockIdx.x;
#pragma unroll
  for (int phase = 0; phase < 4; ++phase) {
    const int* arr = (phase < 2) ? src : dst;
    unsigned* H = (phase < 2) ? Hs : Hd;
    const int r = phase & 1;
    const int lo = r * HALF;
    for (int w = tid; w < HWORDS; w += HT) lds[w] = 0u;
    __syncthreads();
    for (int e = b * HT + tid; e < NE; e += HB * HT) {
      unsigned local = (unsigned)(arr[e] - lo);
      if (local < (unsigned)HALF)
        atomicAdd(&lds[local >> 1], 1u << ((local & 1) * 16));
    }
    __syncthreads();
    for (int w = tid; w < HWORDS; w += HT)
      H[(size_t)b * HALF + r * HWORDS + w] = lds[w];
    __syncthreads();
  }
}

// ---------------- reduce hists -> degrees + norms + per-block dst prefixes + hg zero ----------------
// thread per packed word (2 nodes). Pd[b][w] = exclusive prefix (packed halves, no carry).
__global__ void reduce_norm_kernel(const unsigned* __restrict__ Hs,
                                   const unsigned* __restrict__ Hd,
                                   unsigned* __restrict__ Pd,
                                   int* __restrict__ in_cnt,
                                   float* __restrict__ norm_s,
                                   float* __restrict__ norm_d,
                                   float* __restrict__ hg) {
  int w = blockIdx.x * blockDim.x + threadIdx.x;
  if (blockIdx.x == 0) {  // zero pooled output (512 floats)
    hg[threadIdx.x] = 0.f;
    hg[256 + threadIdx.x] = 0.f;
  }
  if (w >= 2 * HWORDS) return;
  unsigned ss = 0, dd = 0;
  for (int b = 0; b < HB; ++b) {
    Pd[(size_t)b * HALF + w] = dd;
    ss += Hs[(size_t)b * HALF + w];
    dd += Hd[(size_t)b * HALF + w];
  }
  int r = (w >= HWORDS) ? 1 : 0;
  int lw = w - r * HWORDS;
  int n0 = r * HALF + lw * 2;  // packing: low half = even local node
  unsigned s0 = ss & 0xffffu, s1 = ss >> 16;
  unsigned d0 = dd & 0xffffu, d1 = dd >> 16;
  in_cnt[n0] = (int)d0;
  in_cnt[n0 + 1] = (int)d1;
  norm_s[n0] = rsqrtf(fmaxf((float)s0, 1.0f));
  norm_s[n0 + 1] = rsqrtf(fmaxf((float)s1, 1.0f));
  norm_d[n0] = rsqrtf(fmaxf((float)d0, 1.0f));
  norm_d[n0 + 1] = rsqrtf(fmaxf((float)d1, 1.0f));
}

// ---------------- exclusive scan (single block) ----------------
__global__ __launch_bounds__(1024) void scan_kernel(const int* __restrict__ in_cnt,
                                                    int* __restrict__ row_ptr) {
  __shared__ int wsum[16];
  int tid = threadIdx.x;
  int lane = tid & 63, wave = tid >> 6;
  int carry = 0;
  for (int base = 0; base < NN; base += 4096) {
    int i0 = base + tid * 4;
    int v[4];
#pragma unroll
    for (int j = 0; j < 4; ++j) {
      int i = i0 + j;
      v[j] = (i < NN) ? in_cnt[i] : 0;
    }
    int tsum = v[0] + v[1] + v[2] + v[3];
    int incl = tsum;
#pragma unroll
    for (int off = 1; off < 64; off <<= 1) {
      int t = __shfl_up(incl, off, 64);
      if (lane >= off) incl += t;
    }
    if (lane == 63) wsum[wave] = incl;
    __syncthreads();
    int waveoff = 0;
    for (int w = 0; w < wave; ++w) waveoff += wsum[w];
    int chunk_total = 0;
    for (int w = 0; w < 16; ++w) chunk_total += wsum[w];
    int run = carry + waveoff + (incl - tsum);
#pragma unroll
    for (int j = 0; j < 4; ++j) {
      int i = i0 + j;
      if (i < NN) row_ptr[i] = run;
      run += v[j];
    }
    carry += chunk_total;
    __syncthreads();
  }
  if (tid == 0) row_ptr[NN] = carry;
}

// ---------------- CSR fill, atomic-free (rank via LDS, base via Pd prefix) ----------------
__global__ __launch_bounds__(HT) void fill_kernel(const int* __restrict__ src,
                                                  const int* __restrict__ dst,
                                                  const int* __restrict__ row_ptr,
                                                  const unsigned* __restrict__ Pd,
                                                  int* __restrict__ colx) {
  __shared__ unsigned lds[HWORDS];
  const int tid = threadIdx.x;
  const int b = blockIdx.x;
#pragma unroll
  for (int r = 0; r < 2; ++r) {
    const int lo = r * HALF;
    for (int w = tid; w < HWORDS; w += HT) lds[w] = 0u;
    __syncthreads();
    for (int e = b * HT + tid; e < NE; e += HB * HT) {
      int n = dst[e];
      unsigned local = (unsigned)(n - lo);
      if (local < (unsigned)HALF) {
        int sh = (local & 1) * 16;
        unsigned old = atomicAdd(&lds[local >> 1], 1u << sh);
        unsigned rank = (old >> sh) & 0xffffu;
        unsigned pref = (Pd[(size_t)b * HALF + r * HWORDS + (local >> 1)] >> sh) & 0xffffu;
        colx[row_ptr[n] + (int)pref + (int)rank] = src[e];
      }
    }
    __syncthreads();
  }
}

// ---------------- fused prep: cast feat (scaled by norm_s) + swizzle W0/W1 ----------------
// blocks [0,12500): cast; [12500,12532): W0; [12532,12564): W1
__device__ __forceinline__ void swizzleW_body(const float* __restrict__ W,
                                              unsigned short* __restrict__ Wb, int idx) {
  int lane = idx & 63;
  int blk = idx >> 6;
  int kc = blk & 7, nt = blk >> 3;
  int kbase = kc * 32 + (lane >> 4) * 8;
  int col = nt * 16 + (lane & 15);
  ushort4 o0, o1;
  o0.x = f2bf(W[(size_t)(kbase + 0) * DIM + col]);
  o0.y = f2bf(W[(size_t)(kbase + 1) * DIM + col]);
  o0.z = f2bf(W[(size_t)(kbase + 2) * DIM + col]);
  o0.w = f2bf(W[(size_t)(kbase + 3) * DIM + col]);
  o1.x = f2bf(W[(size_t)(kbase + 4) * DIM + col]);
  o1.y = f2bf(W[(size_t)(kbase + 5) * DIM + col]);
  o1.z = f2bf(W[(size_t)(kbase + 6) * DIM + col]);
  o1.w = f2bf(W[(size_t)(kbase + 7) * DIM + col]);
  ((ushort4*)Wb)[idx * 2 + 0] = o0;
  ((ushort4*)Wb)[idx * 2 + 1] = o1;
}

__global__ void prep_kernel(const float* __restrict__ feat, const float* __restrict__ norm_s,
                            unsigned short* __restrict__ featb,
                            const float* __restrict__ W0, unsigned short* __restrict__ Wb0,
                            const float* __restrict__ W1, unsigned short* __restrict__ Wb1) {
  int blk = blockIdx.x;
  if (blk < 12500) {
    int i = blk * 256 + threadIdx.x;  // < NN*DIM/4 exactly
    float s = norm_s[i >> 6];
    float4 v = ((const float4*)feat)[i];
    ushort4 o;
    o.x = f2bf(v.x * s); o.y = f2bf(v.y * s); o.z = f2bf(v.z * s); o.w = f2bf(v.w * s);
    ((ushort4*)featb)[i] = o;
  } else if (blk < 12532) {
    swizzleW_body(W0, Wb0, (blk - 12500) * 256 + threadIdx.x);
  } else {
    swizzleW_body(W1, Wb1, (blk - 12532) * 256 + threadIdx.x);
  }
}

// ---------------- gather-aggregate (X pre-scaled by norm_s): agg[n] = nd[n]*sum X[c] ----------------
__device__ __forceinline__ void acc_row(float* a, uint4 p) {
  a[0] += __uint_as_float(p.x << 16);
  a[1] += __uint_as_float(p.x & 0xffff0000u);
  a[2] += __uint_as_float(p.y << 16);
  a[3] += __uint_as_float(p.y & 0xffff0000u);
  a[4] += __uint_as_float(p.z << 16);
  a[5] += __uint_as_float(p.z & 0xffff0000u);
  a[6] += __uint_as_float(p.w << 16);
  a[7] += __uint_as_float(p.w & 0xffff0000u);
}

__global__ __launch_bounds__(256) void agg_kernel(const unsigned short* __restrict__ X,
                                                  unsigned short* __restrict__ agg,
                                                  const int* __restrict__ row_ptr,
                                                  const int* __restrict__ colx,
                                                  const float* __restrict__ norm_d) {
  int wave = threadIdx.x >> 6;
  int lane = threadIdx.x & 63;
  int half = lane >> 5;
  int sl = lane & 31;
  int node = blockIdx.x * 4 + wave;
  if (node >= NN) return;
  int beg = row_ptr[node];
  int end = row_ptr[node + 1];

  float a[8];
#pragma unroll
  for (int j = 0; j < 8; ++j) a[j] = 0.f;

  int i = beg;
  for (; i + 4 <= end; i += 4) {
    int c0 = colx[i + half];
    int c1 = colx[i + 2 + half];
    uint4 r0 = *(const uint4*)(X + (size_t)c0 * DIM + sl * 8);
    uint4 r1 = *(const uint4*)(X + (size_t)c1 * DIM + sl * 8);
    acc_row(a, r0);
    acc_row(a, r1);
  }
  if (i + 2 <= end) {
    int c = colx[i + half];
    uint4 r = *(const uint4*)(X + (size_t)c * DIM + sl * 8);
    acc_row(a, r);
    i += 2;
  }
  if (i < end && half == 0) {
    int c = colx[i];
    uint4 r = *(const uint4*)(X + (size_t)c * DIM + sl * 8);
    acc_row(a, r);
  }
#pragma unroll
  for (int j = 0; j < 8; ++j) a[j] += __shfl_xor(a[j], 32, 64);

  if (half == 0) {
    float nd = norm_d[node];
    uint4 o;
    o.x = (unsigned)f2bf(a[0] * nd) | ((unsigned)f2bf(a[1] * nd) << 16);
    o.y = (unsigned)f2bf(a[2] * nd) | ((unsigned)f2bf(a[3] * nd) << 16);
    o.z = (unsigned)f2bf(a[4] * nd) | ((unsigned)f2bf(a[5] * nd) << 16);
    o.w = (unsigned)f2bf(a[6] * nd) | ((unsigned)f2bf(a[7] * nd) << 16);
    *(uint4*)(agg + (size_t)node * DIM + sl * 8) = o;
  }
}

// ---------------- MFMA GEMM (32-row tile) + bias + PReLU + coalesced epilogue + pooling ----------------
// Exactly one of C (f32 out) / Cb (norm_s-scaled bf16 out) is non-null.
#define LDSROW 264   // bf16 row stride for A tile
#define FROW 260     // f32 row stride for epilogue staging
__global__ __launch_bounds__(256) void gemm_mfma_kernel(const unsigned short* __restrict__ A,
                                                        const unsigned short* __restrict__ Wb,
                                                        const float* __restrict__ bias,
                                                        const float* __restrict__ prelu_a_ptr,
                                                        const float* __restrict__ norm_s,
                                                        float* __restrict__ C,
                                                        unsigned short* __restrict__ Cb,
                                                        float* __restrict__ hg) {
  __shared__ unsigned short As[32 * LDSROW];  // 16896 B; reused as f32 LF[16][FROW] (16640 B)
  int tid = threadIdx.x;
  int r0 = blockIdx.x * 32;
#pragma unroll
  for (int p = 0; p < 4; ++p) {
    int idx = p * 256 + tid;
    int row = idx >> 5;
    int seg = idx & 31;
    int grow = r0 + row;
    ushort4 v0 = {0, 0, 0, 0}, v1 = {0, 0, 0, 0};
    if (grow < NN) {
      const ushort4* g = (const ushort4*)(A + (size_t)grow * DIM + seg * 8);
      v0 = g[0]; v1 = g[1];
    }
    *(ushort4*)(&As[row * LDSROW + seg * 8 + 0]) = v0;
    *(ushort4*)(&As[row * LDSROW + seg * 8 + 4]) = v1;
  }
  __syncthreads();

  int wave = tid >> 6, lane = tid & 63;
  int quad = lane >> 4, l16 = lane & 15;

  f32x4 acc[2][4];
#pragma unroll
  for (int mt = 0; mt < 2; ++mt)
#pragma unroll
    for (int nti = 0; nti < 4; ++nti)
      acc[mt][nti] = (f32x4){0.f, 0.f, 0.f, 0.f};

#pragma unroll
  for (int kc = 0; kc < 8; ++kc) {
    bf16x8 a[2], b[4];
#pragma unroll
    for (int mt = 0; mt < 2; ++mt)
      a[mt] = *(const bf16x8*)(&As[(mt * 16 + l16) * LDSROW + kc * 32 + quad * 8]);
#pragma unroll
    for (int nti = 0; nti < 4; ++nti) {
      int nt = wave * 4 + nti;
      b[nti] = *(const bf16x8*)(Wb + ((size_t)(nt * 8 + kc) * 64 + lane) * 8);
    }
#pragma unroll
    for (int mt = 0; mt < 2; ++mt)
#pragma unroll
      for (int nti = 0; nti < 4; ++nti)
        acc[mt][nti] = __builtin_amdgcn_mfma_f32_16x16x32_bf16(a[mt], b[nti], acc[mt][nti], 0, 0, 0);
  }

  // bias + PReLU + column sums in registers (C-layout: col=l16, row=mt*16+quad*4+r)
  float pa = *prelu_a_ptr;
  float bv[4], cs[4];
#pragma unroll
  for (int nti = 0; nti < 4; ++nti) {
    bv[nti] = bias[wave * 64 + nti * 16 + l16];
    cs[nti] = 0.f;
  }
#pragma unroll
  for (int mt = 0; mt < 2; ++mt) {
#pragma unroll
    for (int nti = 0; nti < 4; ++nti) {
#pragma unroll
      for (int r = 0; r < 4; ++r) {
        int rowg = r0 + mt * 16 + quad * 4 + r;
        float x = acc[mt][nti][r] + bv[nti];
        x = (x >= 0.f) ? x : pa * x;
        acc[mt][nti][r] = x;
        if (rowg < NN) cs[nti] += x;
      }
    }
  }
#pragma unroll
  for (int nti = 0; nti < 4; ++nti) {
    cs[nti] += __shfl_xor(cs[nti], 16, 64);
    cs[nti] += __shfl_xor(cs[nti], 32, 64);
  }
  if (quad == 0) {
#pragma unroll
    for (int nti = 0; nti < 4; ++nti)
      atomicAdd(&hg[wave * 64 + nti * 16 + l16], cs[nti]);
  }

  // coalesced store epilogue: stage 16-row chunks through LDS
  float* LF = (float*)As;  // [16][FROW]
#pragma unroll
  for (int chunk = 0; chunk < 2; ++chunk) {
    __syncthreads();
#pragma unroll
    for (int nti = 0; nti < 4; ++nti) {
      int colw = wave * 64 + nti * 16 + l16;
#pragma unroll
      for (int r = 0; r < 4; ++r)
        LF[(quad * 4 + r) * FROW + colw] = acc[chunk][nti][r];
    }
    __syncthreads();
    int rowbase = r0 + chunk * 16;
    if (C) {
#pragma unroll
      for (int s = 0; s < 4; ++s) {
        int g = s * 256 + tid;
        int row = g >> 6, cg = g & 63;
        int rowg = rowbase + row;
        if (rowg < NN) {
          float4 v = *(const float4*)&LF[row * FROW + cg * 4];
          *(float4*)(C + (size_t)rowg * DIM + cg * 4) = v;
        }
      }
    }
    if (Cb) {
#pragma unroll
      for (int s = 0; s < 2; ++s) {
        int g = s * 256 + tid;
        int row = g >> 5, cg = g & 31;
        int rowg = rowbase + row;
        if (rowg < NN) {
          float ns = norm_s[rowg];
          float4 v0 = *(const float4*)&LF[row * FROW + cg * 8];
          float4 v1 = *(const float4*)&LF[row * FROW + cg * 8 + 4];
          uint4 o;
          o.x = (unsigned)f2bf(v0.x * ns) | ((unsigned)f2bf(v0.y * ns) << 16);
          o.y = (unsigned)f2bf(v0.z * ns) | ((unsigned)f2bf(v0.w * ns) << 16);
          o.z = (unsigned)f2bf(v1.x * ns) | ((unsigned)f2bf(v1.y * ns) << 16);
          o.w = (unsigned)f2bf(v1.z * ns) | ((unsigned)f2bf(v1.w * ns) << 16);
          *(uint4*)(Cb + (size_t)rowg * DIM + cg * 8) = o;
        }
      }
    }
  }
}

extern "C" void kernel_launch(void* const* d_in, const int* in_sizes, int n_in,
                              void* d_out, int out_size, void* d_ws, size_t ws_size,
                              hipStream_t stream) {
  const float* feat = (const float*)d_in[0];
  const int* src    = (const int*)d_in[1];
  const int* dst    = (const int*)d_in[2];
  const float* W0   = (const float*)d_in[3];
  const float* b0   = (const float*)d_in[4];
  const float* W1   = (const float*)d_in[5];
  const float* b1   = (const float*)d_in[6];
  const float* pa   = (const float*)d_in[7];

  float* out_h = (float*)d_out;                      // [NN, DIM] f32
  float* hg    = out_h + (size_t)NN * DIM;           // [512] f32

  char* w = (char*)d_ws;
  int* in_cnt   = (int*)w;        w += (size_t)NN * 4;
  float* norm_s = (float*)w;      w += (size_t)NN * 4;
  float* norm_d = (float*)w;      w += (size_t)NN * 4;
  int* row_ptr  = (int*)w;        w += (size_t)(NN + 1) * 4;
  int* colx     = (int*)w;        w += (size_t)NE * 4;
  unsigned short* Wb0 = (unsigned short*)w;  w += (size_t)DIM * DIM * 2;
  unsigned short* Wb1 = (unsigned short*)w;  w += (size_t)DIM * DIM * 2;
  uintptr_t ap = ((uintptr_t)w + 255) & ~(uintptr_t)255;
  unsigned short* featb = (unsigned short*)ap;                 // [NN,DIM] bf16 (pre-scaled; reused as h1b)
  unsigned short* aggb  = featb + (size_t)NN * DIM;            // [NN,DIM] bf16
  // aliases (dead before their region's first real use):
  unsigned* Hs = (unsigned*)featb;               // [HB][25000 words] = 12.8 MB
  unsigned* Hd = Hs + (size_t)HB * HALF;         // [HB][25000 words] = 12.8 MB
  unsigned* Pd = (unsigned*)aggb;                // [HB][25000 words] = 12.8 MB (dead after fill)

  hist_kernel<<<HB, HT, 0, stream>>>(src, dst, Hs, Hd);
  reduce_norm_kernel<<<(2 * HWORDS + 255) / 256, 256, 0, stream>>>(Hs, Hd, Pd, in_cnt,
                                                                   norm_s, norm_d, hg);
  prep_kernel<<<12564, 256, 0, stream>>>(feat, norm_s, featb, W0, Wb0, W1, Wb1);
  scan_kernel<<<1, 1024, 0, stream>>>(in_cnt, row_ptr);
  fill_kernel<<<HB, HT, 0, stream>>>(src, dst, row_ptr, Pd, colx);

  // layer 1: only the scaled-bf16 h1 is live
  agg_kernel<<<(NN + 3) / 4, 256, 0, stream>>>(featb, aggb, row_ptr, colx, norm_d);
  gemm_mfma_kernel<<<(NN + 31) / 32, 256, 0, stream>>>(aggb, Wb0, b0, pa, norm_s,
                                                       (float*)nullptr, featb, hg);

  // layer 2: f32 output only
  agg_kernel<<<(NN + 3) / 4, 256, 0, stream>>>(featb, aggb, row_ptr, colx, norm_d);
  gemm_mfma_kernel<<<(NN + 31) / 32, 256, 0, stream>>>(aggb, Wb1, b1, pa, norm_s,
                                                       out_h, (unsigned short*)nullptr, hg + 256);
}